// Round 1
// baseline (550.291 us; speedup 1.0000x reference)
//
#include <hip/hip_runtime.h>

#define N_NODES_C 50000
#define N_EDGES_C 800000
#define K_FEAT 128

// ---------------- CSR build ----------------

__global__ void count_kernel(const int* __restrict__ dst, int* __restrict__ cnt, int E) {
    int i = blockIdx.x * blockDim.x + threadIdx.x;
    if (i < E) atomicAdd(&cnt[dst[i]], 1);
}

// Single-block exclusive scan of cnt -> offs; also rewrites cnt as running cursor start.
__global__ void scan_kernel(int* __restrict__ cnt_cursor, int* __restrict__ offs, int n) {
    __shared__ int buf[2][1024];
    __shared__ int carry_s;
    const int tid = threadIdx.x;
    if (tid == 0) carry_s = 0;
    __syncthreads();
    for (int base = 0; base < n; base += 4096) {
        int idx = base + tid * 4;
        int v[4];
#pragma unroll
        for (int j = 0; j < 4; ++j) v[j] = (idx + j < n) ? cnt_cursor[idx + j] : 0;
        int s = v[0] + v[1] + v[2] + v[3];
        buf[0][tid] = s;
        __syncthreads();
        int sel = 0;
#pragma unroll
        for (int off = 1; off < 1024; off <<= 1) {
            int x = buf[sel][tid];
            if (tid >= off) x += buf[sel][tid - off];
            buf[sel ^ 1][tid] = x;
            sel ^= 1;
            __syncthreads();
        }
        int incl = buf[sel][tid];
        int excl = incl - s + carry_s;
#pragma unroll
        for (int j = 0; j < 4; ++j) {
            if (idx + j < n) { offs[idx + j] = excl; cnt_cursor[idx + j] = excl; }
            excl += v[j];
        }
        __syncthreads();
        if (tid == 1023) carry_s += incl;
        __syncthreads();
    }
    if (tid == 0) offs[n] = carry_s;
}

__global__ void fill_kernel(const int* __restrict__ src, const int* __restrict__ dst,
                            int* __restrict__ cursor, int* __restrict__ ssrc, int E) {
    int i = blockIdx.x * blockDim.x + threadIdx.x;
    if (i < E) {
        int p = atomicAdd(&cursor[dst[i]], 1);
        ssrc[p] = src[i];
    }
}

// ---------------- mean aggregation: one wave (64 lanes) per node ----------------
// h row = 128 floats; lane handles 2 consecutive floats (float2) -> coalesced 512B reads.

__global__ void mean_kernel(const float* __restrict__ h, const int* __restrict__ offs,
                            const int* __restrict__ ssrc, float* __restrict__ mean) {
    const int node = (int)((blockIdx.x * blockDim.x + threadIdx.x) >> 6);
    const int lane = threadIdx.x & 63;
    if (node >= N_NODES_C) return;
    const int beg = offs[node], end = offs[node + 1];
    float a0 = 0.f, a1 = 0.f;
    for (int e = beg; e < end; ++e) {
        const int s = ssrc[e];
        const float2 v = *reinterpret_cast<const float2*>(h + (size_t)s * K_FEAT + lane * 2);
        a0 += v.x;
        a1 += v.y;
    }
    const float inv = (end > beg) ? 1.0f / (float)(end - beg) : 0.f;
    float2 m;
    m.x = a0 * inv;
    m.y = a1 * inv;
    *reinterpret_cast<float2*>(mean + (size_t)node * K_FEAT + lane * 2) = m;
}

// ---------------- fused SAGE GEMM: out = act(h@Ws + mean@Wn + b) ----------------
// K=128 always. NCOL = 128 (layers 0,1) or 64 (layer 2).
// 256 threads: CG = NCOL/8 col-groups x NG node-groups; each thread: 4 nodes x 8 cols.
// Weights + h/mean tiles staged in LDS, k-chunked (KC=32).

template <int NCOL, bool ACT>
__global__ __launch_bounds__(256) void sage_gemm(
    const float* __restrict__ h, const float* __restrict__ mean,
    const float* __restrict__ Ws, const float* __restrict__ Wn,
    const float* __restrict__ bias, float* __restrict__ out, int nNodes) {
    constexpr int K = 128;
    constexpr int KC = 32;
    constexpr int CG = NCOL / 8;   // threads per node-row
    constexpr int NG = 256 / CG;   // node groups per block
    constexpr int NODES = NG * 4;  // nodes per block
    constexpr int HPAD = KC + 4;   // +4 floats: keeps 16B alignment, breaks ng-stride conflicts

    __shared__ float ws_c[KC][NCOL];
    __shared__ float wn_c[KC][NCOL];
    __shared__ float hs[NODES][HPAD];
    __shared__ float ms[NODES][HPAD];

    const int t = threadIdx.x;
    const int cg = t % CG;
    const int ng = t / CG;
    const int node0 = blockIdx.x * NODES;

    float acc[4][8];
#pragma unroll
    for (int i = 0; i < 4; ++i)
#pragma unroll
        for (int j = 0; j < 8; ++j) acc[i][j] = 0.f;

    for (int kc = 0; kc < K; kc += KC) {
        // stage weight chunks (contiguous [KC][NCOL] slabs)
        const float4* gws = reinterpret_cast<const float4*>(Ws + (size_t)kc * NCOL);
        const float4* gwn = reinterpret_cast<const float4*>(Wn + (size_t)kc * NCOL);
        float4* lws = reinterpret_cast<float4*>(&ws_c[0][0]);
        float4* lwn = reinterpret_cast<float4*>(&wn_c[0][0]);
#pragma unroll
        for (int it = 0; it < KC * NCOL / 1024; ++it) {
            lws[t + 256 * it] = gws[t + 256 * it];
            lwn[t + 256 * it] = gwn[t + 256 * it];
        }
        // stage h / mean tiles: NODES rows x KC floats (8 float4 per row)
#pragma unroll
        for (int it = 0; it < NODES * KC / 1024; ++it) {
            int f = t + 256 * it;
            int r = f >> 3;
            int c4 = f & 7;
            int n = node0 + r;
            float4 hv = make_float4(0.f, 0.f, 0.f, 0.f);
            float4 mv = hv;
            if (n < nNodes) {
                hv = *reinterpret_cast<const float4*>(h + (size_t)n * K + kc + c4 * 4);
                mv = *reinterpret_cast<const float4*>(mean + (size_t)n * K + kc + c4 * 4);
            }
            *reinterpret_cast<float4*>(&hs[r][c4 * 4]) = hv;
            *reinterpret_cast<float4*>(&ms[r][c4 * 4]) = mv;
        }
        __syncthreads();

#pragma unroll 8
        for (int k = 0; k < KC; ++k) {
            const float4 w0 = *reinterpret_cast<const float4*>(&ws_c[k][cg * 8]);
            const float4 w1 = *reinterpret_cast<const float4*>(&ws_c[k][cg * 8 + 4]);
            const float4 u0 = *reinterpret_cast<const float4*>(&wn_c[k][cg * 8]);
            const float4 u1 = *reinterpret_cast<const float4*>(&wn_c[k][cg * 8 + 4]);
#pragma unroll
            for (int i = 0; i < 4; ++i) {
                const float hv = hs[ng * 4 + i][k];
                const float mv = ms[ng * 4 + i][k];
                acc[i][0] = fmaf(hv, w0.x, fmaf(mv, u0.x, acc[i][0]));
                acc[i][1] = fmaf(hv, w0.y, fmaf(mv, u0.y, acc[i][1]));
                acc[i][2] = fmaf(hv, w0.z, fmaf(mv, u0.z, acc[i][2]));
                acc[i][3] = fmaf(hv, w0.w, fmaf(mv, u0.w, acc[i][3]));
                acc[i][4] = fmaf(hv, w1.x, fmaf(mv, u1.x, acc[i][4]));
                acc[i][5] = fmaf(hv, w1.y, fmaf(mv, u1.y, acc[i][5]));
                acc[i][6] = fmaf(hv, w1.z, fmaf(mv, u1.z, acc[i][6]));
                acc[i][7] = fmaf(hv, w1.w, fmaf(mv, u1.w, acc[i][7]));
            }
        }
        __syncthreads();
    }

    float bv[8];
#pragma unroll
    for (int j = 0; j < 8; ++j) bv[j] = bias[cg * 8 + j];

#pragma unroll
    for (int i = 0; i < 4; ++i) {
        const int n = node0 + ng * 4 + i;
        if (n < nNodes) {
            float o[8];
#pragma unroll
            for (int j = 0; j < 8; ++j) {
                o[j] = acc[i][j] + bv[j];
                if (ACT) o[j] = fmaxf(o[j], 0.f);
            }
            float4 o0 = make_float4(o[0], o[1], o[2], o[3]);
            float4 o1 = make_float4(o[4], o[5], o[6], o[7]);
            *reinterpret_cast<float4*>(out + (size_t)n * NCOL + cg * 8) = o0;
            *reinterpret_cast<float4*>(out + (size_t)n * NCOL + cg * 8 + 4) = o1;
        }
    }
}

// ---------------- launch ----------------

extern "C" void kernel_launch(void* const* d_in, const int* in_sizes, int n_in,
                              void* d_out, int out_size, void* d_ws, size_t ws_size,
                              hipStream_t stream) {
    const float* feat = (const float*)d_in[0];
    const int* src = (const int*)d_in[1];
    const int* dst = (const int*)d_in[2];
    const float* Ws0 = (const float*)d_in[3];
    const float* Wn0 = (const float*)d_in[4];
    const float* b0 = (const float*)d_in[5];
    const float* Ws1 = (const float*)d_in[6];
    const float* Wn1 = (const float*)d_in[7];
    const float* b1 = (const float*)d_in[8];
    const float* Ws2 = (const float*)d_in[9];
    const float* Wn2 = (const float*)d_in[10];
    const float* b2 = (const float*)d_in[11];
    float* out = (float*)d_out;

    auto align_up = [](size_t x) { return (x + 255) & ~(size_t)255; };
    char* w = (char*)d_ws;
    int* cursor = (int*)w;
    w += align_up((size_t)N_NODES_C * 4);
    int* offs = (int*)w;
    w += align_up((size_t)(N_NODES_C + 1) * 4);
    int* ssrc = (int*)w;
    w += align_up((size_t)N_EDGES_C * 4);
    float* mean = (float*)w;
    w += align_up((size_t)N_NODES_C * K_FEAT * 4);
    float* hA = (float*)w;
    w += align_up((size_t)N_NODES_C * K_FEAT * 4);

    // ---- CSR build (once; reused by all 3 layers) ----
    hipMemsetAsync(cursor, 0, (size_t)N_NODES_C * 4, stream);
    count_kernel<<<(N_EDGES_C + 255) / 256, 256, 0, stream>>>(dst, cursor, N_EDGES_C);
    scan_kernel<<<1, 1024, 0, stream>>>(cursor, offs, N_NODES_C);
    fill_kernel<<<(N_EDGES_C + 255) / 256, 256, 0, stream>>>(src, dst, cursor, ssrc, N_EDGES_C);

    const int meanBlocks = (N_NODES_C * 64 + 255) / 256;
    const int gemmBlocks128 = (N_NODES_C + 63) / 64;
    const int gemmBlocks64 = (N_NODES_C + 127) / 128;

    // ---- layer 0: features -> hA ----
    mean_kernel<<<meanBlocks, 256, 0, stream>>>(feat, offs, ssrc, mean);
    sage_gemm<128, true><<<gemmBlocks128, 256, 0, stream>>>(feat, mean, Ws0, Wn0, b0, hA, N_NODES_C);

    // ---- layer 1: hA -> hA (in-place is safe: each block writes only its own
    //      rows, strictly after its final read of those rows) ----
    mean_kernel<<<meanBlocks, 256, 0, stream>>>(hA, offs, ssrc, mean);
    sage_gemm<128, true><<<gemmBlocks128, 256, 0, stream>>>(hA, mean, Ws1, Wn1, b1, hA, N_NODES_C);

    // ---- layer 2: hA -> out (no activation) ----
    mean_kernel<<<meanBlocks, 256, 0, stream>>>(hA, offs, ssrc, mean);
    sage_gemm<64, false><<<gemmBlocks64, 256, 0, stream>>>(hA, mean, Ws2, Wn2, b2, out, N_NODES_C);
}

// Round 2
// 381.287 us; speedup vs baseline: 1.4432x; 1.4432x over previous
//
#include <hip/hip_runtime.h>

#define N_NODES_C 50000
#define N_EDGES_C 800000
#define K_FEAT 128

typedef unsigned short ushort_t;
typedef unsigned int uint_t;

static __device__ __forceinline__ ushort_t f2bf(float x) {
    uint_t u = __float_as_uint(x);
    uint_t r = (u + 0x7fffu + ((u >> 16) & 1u)) >> 16;  // RNE
    return (ushort_t)r;
}
static __device__ __forceinline__ float bf_lo(uint_t u) { return __uint_as_float(u << 16); }
static __device__ __forceinline__ float bf_hi(uint_t u) { return __uint_as_float(u & 0xffff0000u); }

// ---------------- CSR build ----------------

__global__ void count_kernel(const int* __restrict__ dst, int* __restrict__ cnt, int E) {
    int i = blockIdx.x * blockDim.x + threadIdx.x;
    if (i < E) atomicAdd(&cnt[dst[i]], 1);
}

// Hierarchical scan, step 1: 256 threads x 4 elems = 1024/block.
// Writes per-block exclusive prefix into offs, block totals into bsums.
__global__ void scan1_kernel(const int* __restrict__ cnt, int* __restrict__ offs,
                             int* __restrict__ bsums, int n) {
    const int t = threadIdx.x;
    const int lane = t & 63;
    const int wid = t >> 6;
    const int base = blockIdx.x * 1024 + t * 4;
    int v[4];
#pragma unroll
    for (int j = 0; j < 4; ++j) v[j] = (base + j < n) ? cnt[base + j] : 0;
    int s = v[0] + v[1] + v[2] + v[3];
    // wave-inclusive scan of s
    int x = s;
#pragma unroll
    for (int off = 1; off < 64; off <<= 1) {
        int y = __shfl_up(x, off, 64);
        if (lane >= off) x += y;
    }
    __shared__ int wsum[4];
    if (lane == 63) wsum[wid] = x;
    __syncthreads();
    int wpre = 0;
#pragma unroll
    for (int w = 0; w < 4; ++w)
        if (w < wid) wpre += wsum[w];
    int run = wpre + x - s;  // exclusive prefix for this thread's first elem
#pragma unroll
    for (int j = 0; j < 4; ++j) {
        if (base + j < n) offs[base + j] = run;
        run += v[j];
    }
    if (t == 255) bsums[blockIdx.x] = wpre + x;
}

// step 2: one wave scans the block sums (nb <= 64) -> exclusive.
__global__ void scan2_kernel(int* __restrict__ bsums, int nb) {
    const int lane = threadIdx.x;
    int v = (lane < nb) ? bsums[lane] : 0;
    int x = v;
#pragma unroll
    for (int off = 1; off < 64; off <<= 1) {
        int y = __shfl_up(x, off, 64);
        if (lane >= off) x += y;
    }
    if (lane < nb) bsums[lane] = x - v;
}

// step 3: add block offsets; mirror into cursor; write offs[n].
__global__ void scan3_kernel(int* __restrict__ offs, int* __restrict__ cursor,
                             const int* __restrict__ bsums, int n, int total) {
    const int t = threadIdx.x;
    const int base = blockIdx.x * 1024 + t * 4;
    const int add = bsums[blockIdx.x];
#pragma unroll
    for (int j = 0; j < 4; ++j) {
        int idx = base + j;
        if (idx < n) {
            int o = offs[idx] + add;
            offs[idx] = o;
            cursor[idx] = o;
        }
    }
    if (blockIdx.x == 0 && t == 0) offs[n] = total;
}

__global__ void fill_kernel(const int* __restrict__ src, const int* __restrict__ dst,
                            int* __restrict__ cursor, int* __restrict__ ssrc, int E) {
    int i = blockIdx.x * blockDim.x + threadIdx.x;
    if (i < E) {
        int p = atomicAdd(&cursor[dst[i]], 1);
        ssrc[p] = src[i];
    }
}

// ---------------- fp32 -> bf16 row copy (features, once) ----------------

__global__ void f2bf_kernel(const float* __restrict__ in, ushort_t* __restrict__ out, int n4) {
    int i = blockIdx.x * blockDim.x + threadIdx.x;
    if (i < n4) {
        float4 v = reinterpret_cast<const float4*>(in)[i];
        ushort4 o;
        o.x = f2bf(v.x);
        o.y = f2bf(v.y);
        o.z = f2bf(v.z);
        o.w = f2bf(v.w);
        reinterpret_cast<ushort4*>(out)[i] = o;
    }
}

// ---------------- mean aggregation: one wave per node, bf16 rows ----------------
// Row = 128 bf16 = 256B. Lane handles 2 consecutive cols (one u32 load).
// Edge loop unrolled x4 with independent accumulators for MLP.

__global__ void mean_kernel(const ushort_t* __restrict__ hb, const int* __restrict__ offs,
                            const int* __restrict__ ssrc, float* __restrict__ mean) {
    const int node = (int)((blockIdx.x * blockDim.x + threadIdx.x) >> 6);
    const int lane = threadIdx.x & 63;
    if (node >= N_NODES_C) return;
    const int beg = offs[node], end = offs[node + 1];
    const ushort_t* base = hb + lane * 2;
    float a0 = 0.f, a1 = 0.f, b0 = 0.f, b1 = 0.f;
    float c0 = 0.f, c1 = 0.f, d0 = 0.f, d1 = 0.f;
    int e = beg;
    for (; e + 4 <= end; e += 4) {
        const int s0 = ssrc[e], s1 = ssrc[e + 1], s2 = ssrc[e + 2], s3 = ssrc[e + 3];
        const uint_t u0 = *reinterpret_cast<const uint_t*>(base + (size_t)s0 * K_FEAT);
        const uint_t u1 = *reinterpret_cast<const uint_t*>(base + (size_t)s1 * K_FEAT);
        const uint_t u2 = *reinterpret_cast<const uint_t*>(base + (size_t)s2 * K_FEAT);
        const uint_t u3 = *reinterpret_cast<const uint_t*>(base + (size_t)s3 * K_FEAT);
        a0 += bf_lo(u0); a1 += bf_hi(u0);
        b0 += bf_lo(u1); b1 += bf_hi(u1);
        c0 += bf_lo(u2); c1 += bf_hi(u2);
        d0 += bf_lo(u3); d1 += bf_hi(u3);
    }
    for (; e < end; ++e) {
        const int s0 = ssrc[e];
        const uint_t u0 = *reinterpret_cast<const uint_t*>(base + (size_t)s0 * K_FEAT);
        a0 += bf_lo(u0); a1 += bf_hi(u0);
    }
    const float inv = (end > beg) ? 1.0f / (float)(end - beg) : 0.f;
    float2 m;
    m.x = ((a0 + b0) + (c0 + d0)) * inv;
    m.y = ((a1 + b1) + (c1 + d1)) * inv;
    *reinterpret_cast<float2*>(mean + (size_t)node * K_FEAT + lane * 2) = m;
}

// ---------------- fused SAGE GEMM: out = act(h@Ws + mean@Wn + b) ----------------
// K=128. NCOL = 128 (layers 0,1) or 64 (layer 2). fp32 math.
// Optionally emits a bf16 copy of the output (next layer's gather operand).

template <int NCOL, bool ACT, bool WRITE_BF>
__global__ __launch_bounds__(256) void sage_gemm(
    const float* __restrict__ h, const float* __restrict__ mean,
    const float* __restrict__ Ws, const float* __restrict__ Wn,
    const float* __restrict__ bias, float* __restrict__ out,
    ushort_t* __restrict__ outb, int nNodes) {
    constexpr int K = 128;
    constexpr int KC = 32;
    constexpr int CG = NCOL / 8;   // threads per node-row
    constexpr int NG = 256 / CG;   // node groups per block
    constexpr int NODES = NG * 4;  // nodes per block
    constexpr int HPAD = KC + 4;

    __shared__ float ws_c[KC][NCOL];
    __shared__ float wn_c[KC][NCOL];
    __shared__ float hs[NODES][HPAD];
    __shared__ float ms[NODES][HPAD];

    const int t = threadIdx.x;
    const int cg = t % CG;
    const int ng = t / CG;
    const int node0 = blockIdx.x * NODES;

    float acc[4][8];
#pragma unroll
    for (int i = 0; i < 4; ++i)
#pragma unroll
        for (int j = 0; j < 8; ++j) acc[i][j] = 0.f;

    for (int kc = 0; kc < K; kc += KC) {
        const float4* gws = reinterpret_cast<const float4*>(Ws + (size_t)kc * NCOL);
        const float4* gwn = reinterpret_cast<const float4*>(Wn + (size_t)kc * NCOL);
        float4* lws = reinterpret_cast<float4*>(&ws_c[0][0]);
        float4* lwn = reinterpret_cast<float4*>(&wn_c[0][0]);
#pragma unroll
        for (int it = 0; it < KC * NCOL / 1024; ++it) {
            lws[t + 256 * it] = gws[t + 256 * it];
            lwn[t + 256 * it] = gwn[t + 256 * it];
        }
#pragma unroll
        for (int it = 0; it < NODES * KC / 1024; ++it) {
            int f = t + 256 * it;
            int r = f >> 3;
            int c4 = f & 7;
            int n = node0 + r;
            float4 hv = make_float4(0.f, 0.f, 0.f, 0.f);
            float4 mv = hv;
            if (n < nNodes) {
                hv = *reinterpret_cast<const float4*>(h + (size_t)n * K + kc + c4 * 4);
                mv = *reinterpret_cast<const float4*>(mean + (size_t)n * K + kc + c4 * 4);
            }
            *reinterpret_cast<float4*>(&hs[r][c4 * 4]) = hv;
            *reinterpret_cast<float4*>(&ms[r][c4 * 4]) = mv;
        }
        __syncthreads();

#pragma unroll 8
        for (int k = 0; k < KC; ++k) {
            const float4 w0 = *reinterpret_cast<const float4*>(&ws_c[k][cg * 8]);
            const float4 w1 = *reinterpret_cast<const float4*>(&ws_c[k][cg * 8 + 4]);
            const float4 u0 = *reinterpret_cast<const float4*>(&wn_c[k][cg * 8]);
            const float4 u1 = *reinterpret_cast<const float4*>(&wn_c[k][cg * 8 + 4]);
#pragma unroll
            for (int i = 0; i < 4; ++i) {
                const float hv = hs[ng * 4 + i][k];
                const float mv = ms[ng * 4 + i][k];
                acc[i][0] = fmaf(hv, w0.x, fmaf(mv, u0.x, acc[i][0]));
                acc[i][1] = fmaf(hv, w0.y, fmaf(mv, u0.y, acc[i][1]));
                acc[i][2] = fmaf(hv, w0.z, fmaf(mv, u0.z, acc[i][2]));
                acc[i][3] = fmaf(hv, w0.w, fmaf(mv, u0.w, acc[i][3]));
                acc[i][4] = fmaf(hv, w1.x, fmaf(mv, u1.x, acc[i][4]));
                acc[i][5] = fmaf(hv, w1.y, fmaf(mv, u1.y, acc[i][5]));
                acc[i][6] = fmaf(hv, w1.z, fmaf(mv, u1.z, acc[i][6]));
                acc[i][7] = fmaf(hv, w1.w, fmaf(mv, u1.w, acc[i][7]));
            }
        }
        __syncthreads();
    }

    float bv[8];
#pragma unroll
    for (int j = 0; j < 8; ++j) bv[j] = bias[cg * 8 + j];

#pragma unroll
    for (int i = 0; i < 4; ++i) {
        const int n = node0 + ng * 4 + i;
        if (n < nNodes) {
            float o[8];
#pragma unroll
            for (int j = 0; j < 8; ++j) {
                o[j] = acc[i][j] + bv[j];
                if (ACT) o[j] = fmaxf(o[j], 0.f);
            }
            float4 o0 = make_float4(o[0], o[1], o[2], o[3]);
            float4 o1 = make_float4(o[4], o[5], o[6], o[7]);
            *reinterpret_cast<float4*>(out + (size_t)n * NCOL + cg * 8) = o0;
            *reinterpret_cast<float4*>(out + (size_t)n * NCOL + cg * 8 + 4) = o1;
            if (WRITE_BF) {
                ushort4 p0, p1;
                p0.x = f2bf(o[0]); p0.y = f2bf(o[1]); p0.z = f2bf(o[2]); p0.w = f2bf(o[3]);
                p1.x = f2bf(o[4]); p1.y = f2bf(o[5]); p1.z = f2bf(o[6]); p1.w = f2bf(o[7]);
                *reinterpret_cast<ushort4*>(outb + (size_t)n * NCOL + cg * 8) = p0;
                *reinterpret_cast<ushort4*>(outb + (size_t)n * NCOL + cg * 8 + 4) = p1;
            }
        }
    }
}

// ---------------- launch ----------------

extern "C" void kernel_launch(void* const* d_in, const int* in_sizes, int n_in,
                              void* d_out, int out_size, void* d_ws, size_t ws_size,
                              hipStream_t stream) {
    const float* feat = (const float*)d_in[0];
    const int* src = (const int*)d_in[1];
    const int* dst = (const int*)d_in[2];
    const float* Ws0 = (const float*)d_in[3];
    const float* Wn0 = (const float*)d_in[4];
    const float* b0 = (const float*)d_in[5];
    const float* Ws1 = (const float*)d_in[6];
    const float* Wn1 = (const float*)d_in[7];
    const float* b1 = (const float*)d_in[8];
    const float* Ws2 = (const float*)d_in[9];
    const float* Wn2 = (const float*)d_in[10];
    const float* b2 = (const float*)d_in[11];
    float* out = (float*)d_out;

    auto align_up = [](size_t x) { return (x + 255) & ~(size_t)255; };
    char* w = (char*)d_ws;
    int* cursor = (int*)w;  w += align_up((size_t)N_NODES_C * 4);
    int* offs = (int*)w;    w += align_up((size_t)(N_NODES_C + 1) * 4);
    int* bsums = (int*)w;   w += align_up(64 * 4);
    int* ssrc = (int*)w;    w += align_up((size_t)N_EDGES_C * 4);
    float* mean = (float*)w; w += align_up((size_t)N_NODES_C * K_FEAT * 4);
    float* hA = (float*)w;   w += align_up((size_t)N_NODES_C * K_FEAT * 4);
    ushort_t* featb = (ushort_t*)w; w += align_up((size_t)N_NODES_C * K_FEAT * 2);
    ushort_t* hb = (ushort_t*)w;    w += align_up((size_t)N_NODES_C * K_FEAT * 2);

    const int scanBlocks = (N_NODES_C + 1023) / 1024;  // 49

    // ---- CSR build ----
    hipMemsetAsync(cursor, 0, (size_t)N_NODES_C * 4, stream);
    count_kernel<<<(N_EDGES_C + 255) / 256, 256, 0, stream>>>(dst, cursor, N_EDGES_C);
    scan1_kernel<<<scanBlocks, 256, 0, stream>>>(cursor, offs, bsums, N_NODES_C);
    scan2_kernel<<<1, 64, 0, stream>>>(bsums, scanBlocks);
    scan3_kernel<<<scanBlocks, 256, 0, stream>>>(offs, cursor, bsums, N_NODES_C, N_EDGES_C);
    fill_kernel<<<(N_EDGES_C + 255) / 256, 256, 0, stream>>>(src, dst, cursor, ssrc, N_EDGES_C);

    // ---- features -> bf16 (gather operand) ----
    const int n4 = N_NODES_C * K_FEAT / 4;
    f2bf_kernel<<<(n4 + 255) / 256, 256, 0, stream>>>(feat, featb, n4);

    const int meanBlocks = (N_NODES_C * 64 + 255) / 256;
    const int gemmBlocks128 = (N_NODES_C + 63) / 64;
    const int gemmBlocks64 = (N_NODES_C + 127) / 128;

    // ---- layer 0 ----
    mean_kernel<<<meanBlocks, 256, 0, stream>>>(featb, offs, ssrc, mean);
    sage_gemm<128, true, true><<<gemmBlocks128, 256, 0, stream>>>(
        feat, mean, Ws0, Wn0, b0, hA, hb, N_NODES_C);

    // ---- layer 1 (hA in-place; hb re-written after its last read) ----
    mean_kernel<<<meanBlocks, 256, 0, stream>>>(hb, offs, ssrc, mean);
    sage_gemm<128, true, true><<<gemmBlocks128, 256, 0, stream>>>(
        hA, mean, Ws1, Wn1, b1, hA, hb, N_NODES_C);

    // ---- layer 2 ----
    mean_kernel<<<meanBlocks, 256, 0, stream>>>(hb, offs, ssrc, mean);
    sage_gemm<64, false, false><<<gemmBlocks64, 256, 0, stream>>>(
        hA, mean, Ws2, Wn2, b2, out, nullptr, N_NODES_C);
}

// Round 3
// 316.073 us; speedup vs baseline: 1.7410x; 1.2063x over previous
//
#include <hip/hip_runtime.h>
#include <hip/hip_fp16.h>

#define N_NODES_C 50000
#define N_EDGES_C 800000
#define K_FEAT 128
#define HM_STRIDE 256  // [h(128) | mean(128)] fp16 per node

typedef unsigned int uint_t;
typedef _Float16 half8 __attribute__((ext_vector_type(8)));
typedef _Float16 half4 __attribute__((ext_vector_type(4)));
typedef float f32x4 __attribute__((ext_vector_type(4)));

// ---------------- CSR build ----------------

__global__ void count_kernel(const int* __restrict__ dst, int* __restrict__ cnt, int E) {
    int i = blockIdx.x * blockDim.x + threadIdx.x;
    if (i < E) atomicAdd(&cnt[dst[i]], 1);
}

// Hierarchical scan, step 1: 256 threads x 4 elems = 1024/block.
__global__ void scan1_kernel(const int* __restrict__ cnt, int* __restrict__ offs,
                             int* __restrict__ bsums, int n) {
    const int t = threadIdx.x;
    const int lane = t & 63;
    const int wid = t >> 6;
    const int base = blockIdx.x * 1024 + t * 4;
    int v[4];
#pragma unroll
    for (int j = 0; j < 4; ++j) v[j] = (base + j < n) ? cnt[base + j] : 0;
    int s = v[0] + v[1] + v[2] + v[3];
    int x = s;
#pragma unroll
    for (int off = 1; off < 64; off <<= 1) {
        int y = __shfl_up(x, off, 64);
        if (lane >= off) x += y;
    }
    __shared__ int wsum[4];
    if (lane == 63) wsum[wid] = x;
    __syncthreads();
    int wpre = 0;
#pragma unroll
    for (int w = 0; w < 4; ++w)
        if (w < wid) wpre += wsum[w];
    int run = wpre + x - s;
#pragma unroll
    for (int j = 0; j < 4; ++j) {
        if (base + j < n) offs[base + j] = run;
        run += v[j];
    }
    if (t == 255) bsums[blockIdx.x] = wpre + x;
}

__global__ void scan2_kernel(int* __restrict__ bsums, int nb) {
    const int lane = threadIdx.x;
    int v = (lane < nb) ? bsums[lane] : 0;
    int x = v;
#pragma unroll
    for (int off = 1; off < 64; off <<= 1) {
        int y = __shfl_up(x, off, 64);
        if (lane >= off) x += y;
    }
    if (lane < nb) bsums[lane] = x - v;
}

__global__ void scan3_kernel(int* __restrict__ offs, int* __restrict__ cursor,
                             const int* __restrict__ bsums, int n, int total) {
    const int t = threadIdx.x;
    const int base = blockIdx.x * 1024 + t * 4;
    const int add = bsums[blockIdx.x];
#pragma unroll
    for (int j = 0; j < 4; ++j) {
        int idx = base + j;
        if (idx < n) {
            int o = offs[idx] + add;
            offs[idx] = o;
            cursor[idx] = o;
        }
    }
    if (blockIdx.x == 0 && t == 0) offs[n] = total;
}

__global__ void fill_kernel(const int* __restrict__ src, const int* __restrict__ dst,
                            int* __restrict__ cursor, int* __restrict__ ssrc, int E) {
    int i = blockIdx.x * blockDim.x + threadIdx.x;
    if (i < E) {
        int p = atomicAdd(&cursor[dst[i]], 1);
        ssrc[p] = src[i];
    }
}

// ---------------- fp32 features -> fp16 h-part of hm0 ----------------

__global__ void f2h_kernel(const float* __restrict__ in, _Float16* __restrict__ hm, int n4) {
    int i = blockIdx.x * blockDim.x + threadIdx.x;
    if (i < n4) {
        float4 v = reinterpret_cast<const float4*>(in)[i];
        int n = i >> 5, c4 = i & 31;  // 32 float4 per 128-col row
        half4 o;
        o.x = (_Float16)v.x; o.y = (_Float16)v.y; o.z = (_Float16)v.z; o.w = (_Float16)v.w;
        *reinterpret_cast<half4*>(hm + (size_t)n * HM_STRIDE + c4 * 4) = o;
    }
}

// ---------------- weight convert+transpose: WT[c][k] = Wcat[k][c], fp16 ----------------
// Wcat rows 0..127 = Ws, 128..255 = Wn.

__global__ void wconv_kernel(const float* __restrict__ Ws, const float* __restrict__ Wn,
                             _Float16* __restrict__ WT, int ncol) {
    int idx = blockIdx.x * blockDim.x + threadIdx.x;
    if (idx >= ncol * 256) return;
    int k = idx & 255, c = idx >> 8;
    float v = (k < 128) ? Ws[(size_t)k * ncol + c] : Wn[(size_t)(k - 128) * ncol + c];
    WT[idx] = (_Float16)v;
}

// ---------------- mean aggregation: one wave per node, fp16 rows in hm ----------------
// Reads h-part (cols 0..127), writes mean-part (cols 128..255) of the SAME hm buffer.

__global__ void mean_kernel(_Float16* __restrict__ hm, const int* __restrict__ offs,
                            const int* __restrict__ ssrc) {
    const int node = (int)((blockIdx.x * blockDim.x + threadIdx.x) >> 6);
    const int lane = threadIdx.x & 63;
    if (node >= N_NODES_C) return;
    const int beg = offs[node], end = offs[node + 1];
    const _Float16* base = hm + lane * 2;
    float a0 = 0.f, a1 = 0.f, b0 = 0.f, b1 = 0.f;
    float c0 = 0.f, c1 = 0.f, d0 = 0.f, d1 = 0.f;
    int e = beg;
    for (; e + 4 <= end; e += 4) {
        const int s0 = ssrc[e], s1 = ssrc[e + 1], s2 = ssrc[e + 2], s3 = ssrc[e + 3];
        float2 v0 = __half22float2(*reinterpret_cast<const __half2*>(base + (size_t)s0 * HM_STRIDE));
        float2 v1 = __half22float2(*reinterpret_cast<const __half2*>(base + (size_t)s1 * HM_STRIDE));
        float2 v2 = __half22float2(*reinterpret_cast<const __half2*>(base + (size_t)s2 * HM_STRIDE));
        float2 v3 = __half22float2(*reinterpret_cast<const __half2*>(base + (size_t)s3 * HM_STRIDE));
        a0 += v0.x; a1 += v0.y;
        b0 += v1.x; b1 += v1.y;
        c0 += v2.x; c1 += v2.y;
        d0 += v3.x; d1 += v3.y;
    }
    for (; e < end; ++e) {
        const int s0 = ssrc[e];
        float2 v0 = __half22float2(*reinterpret_cast<const __half2*>(base + (size_t)s0 * HM_STRIDE));
        a0 += v0.x; a1 += v0.y;
    }
    const float inv = (end > beg) ? 1.0f / (float)(end - beg) : 0.f;
    float2 m;
    m.x = ((a0 + b0) + (c0 + d0)) * inv;
    m.y = ((a1 + b1) + (c1 + d1)) * inv;
    *reinterpret_cast<__half2*>(hm + (size_t)node * HM_STRIDE + 128 + lane * 2) =
        __float22half2_rn(m);
}

// ---------------- MFMA GEMM: out = act(hm @ Wcat + b), K=256 ----------------
// Block: 256 threads (4 waves), 64 rows x NCOL. Wave w owns rows [w*16, w*16+16).
// No LDS: A-frags straight from global (each row read by one wave only);
// B-frags from WT (64-128KB, L2-hot). mfma_f32_16x16x32_f16, fp32 accum.
// D[i][j] = sum_k A[i][k]*B[j][k]; A lane: row=l&15, k=(l>>4)*8+j; B lane: col=l&15.
// C/D: col=lane&15, row=(lane>>4)*4+reg (m89-verified mapping).

template <int NCOL, bool ACT, bool OUT_FP32>
__global__ __launch_bounds__(256) void sage_mfma(
    const _Float16* __restrict__ hm,  // [n][256]
    const _Float16* __restrict__ WT,  // [NCOL][256]
    const float* __restrict__ bias,
    float* __restrict__ outf,         // OUT_FP32: [n][NCOL]
    _Float16* __restrict__ outh,      // else: next layer's hm, h-part
    int nNodes) {
    constexpr int CF = NCOL / 16;  // col frags: 8 or 4
    const int wid = threadIdx.x >> 6;
    const int lane = threadIdx.x & 63;
    const int r0 = blockIdx.x * 64 + wid * 16;
    const int arow = r0 + (lane & 15);
    const int arow_c = (arow < nNodes) ? arow : 0;  // clamp; OOB rows discarded on store
    const int koff = (lane >> 4) * 8;

    const _Float16* aptr = hm + (size_t)arow_c * HM_STRIDE + koff;
    const _Float16* bbase = WT + (size_t)(lane & 15) * 256 + koff;

    f32x4 acc[CF];
#pragma unroll
    for (int c = 0; c < CF; ++c) acc[c] = {0.f, 0.f, 0.f, 0.f};

#pragma unroll
    for (int ks = 0; ks < 8; ++ks) {
        half8 a = *reinterpret_cast<const half8*>(aptr + ks * 32);
#pragma unroll
        for (int c = 0; c < CF; ++c) {
            half8 b = *reinterpret_cast<const half8*>(bbase + (size_t)c * 16 * 256 + ks * 32);
            acc[c] = __builtin_amdgcn_mfma_f32_16x16x32_f16(a, b, acc[c], 0, 0, 0);
        }
    }

    const int orow_base = r0 + ((lane >> 4) << 2);
    const int ocol = lane & 15;
#pragma unroll
    for (int c = 0; c < CF; ++c) {
        const int col = c * 16 + ocol;
        const float bv = bias[col];
#pragma unroll
        for (int reg = 0; reg < 4; ++reg) {
            const int row = orow_base + reg;
            if (row < nNodes) {
                float v = acc[c][reg] + bv;
                if (ACT) v = fmaxf(v, 0.f);
                if (OUT_FP32) outf[(size_t)row * NCOL + col] = v;
                else outh[(size_t)row * HM_STRIDE + col] = (_Float16)v;
            }
        }
    }
}

// ---------------- launch ----------------

extern "C" void kernel_launch(void* const* d_in, const int* in_sizes, int n_in,
                              void* d_out, int out_size, void* d_ws, size_t ws_size,
                              hipStream_t stream) {
    const float* feat = (const float*)d_in[0];
    const int* src = (const int*)d_in[1];
    const int* dst = (const int*)d_in[2];
    const float* Ws0 = (const float*)d_in[3];
    const float* Wn0 = (const float*)d_in[4];
    const float* b0 = (const float*)d_in[5];
    const float* Ws1 = (const float*)d_in[6];
    const float* Wn1 = (const float*)d_in[7];
    const float* b1 = (const float*)d_in[8];
    const float* Ws2 = (const float*)d_in[9];
    const float* Wn2 = (const float*)d_in[10];
    const float* b2 = (const float*)d_in[11];
    float* out = (float*)d_out;

    auto align_up = [](size_t x) { return (x + 255) & ~(size_t)255; };
    char* w = (char*)d_ws;
    int* cursor = (int*)w;  w += align_up((size_t)N_NODES_C * 4);
    int* offs = (int*)w;    w += align_up((size_t)(N_NODES_C + 1) * 4);
    int* bsums = (int*)w;   w += align_up(64 * 4);
    int* ssrc = (int*)w;    w += align_up((size_t)N_EDGES_C * 4);
    _Float16* hm0 = (_Float16*)w; w += align_up((size_t)N_NODES_C * HM_STRIDE * 2);
    _Float16* hm1 = (_Float16*)w; w += align_up((size_t)N_NODES_C * HM_STRIDE * 2);
    _Float16* WT0 = (_Float16*)w; w += align_up((size_t)128 * 256 * 2);
    _Float16* WT1 = (_Float16*)w; w += align_up((size_t)128 * 256 * 2);
    _Float16* WT2 = (_Float16*)w; w += align_up((size_t)64 * 256 * 2);
    _Float16* hm2 = hm0;  // hm0 is dead after GEMM0 reads it

    const int scanBlocks = (N_NODES_C + 1023) / 1024;  // 49

    // ---- CSR build ----
    hipMemsetAsync(cursor, 0, (size_t)N_NODES_C * 4, stream);
    count_kernel<<<(N_EDGES_C + 255) / 256, 256, 0, stream>>>(dst, cursor, N_EDGES_C);
    scan1_kernel<<<scanBlocks, 256, 0, stream>>>(cursor, offs, bsums, N_NODES_C);
    scan2_kernel<<<1, 64, 0, stream>>>(bsums, scanBlocks);
    scan3_kernel<<<scanBlocks, 256, 0, stream>>>(offs, cursor, bsums, N_NODES_C, N_EDGES_C);
    fill_kernel<<<(N_EDGES_C + 255) / 256, 256, 0, stream>>>(src, dst, cursor, ssrc, N_EDGES_C);

    // ---- features -> fp16 into hm0 h-part; weights -> fp16 transposed ----
    const int n4 = N_NODES_C * K_FEAT / 4;
    f2h_kernel<<<(n4 + 255) / 256, 256, 0, stream>>>(feat, hm0, n4);
    wconv_kernel<<<(128 * 256 + 255) / 256, 256, 0, stream>>>(Ws0, Wn0, WT0, 128);
    wconv_kernel<<<(128 * 256 + 255) / 256, 256, 0, stream>>>(Ws1, Wn1, WT1, 128);
    wconv_kernel<<<(64 * 256 + 255) / 256, 256, 0, stream>>>(Ws2, Wn2, WT2, 64);

    const int meanBlocks = (N_NODES_C * 64 + 255) / 256;
    const int gemmBlocks = (N_NODES_C + 63) / 64;  // 782

    // ---- layer 0 ----
    mean_kernel<<<meanBlocks, 256, 0, stream>>>(hm0, offs, ssrc);
    sage_mfma<128, true, false><<<gemmBlocks, 256, 0, stream>>>(
        hm0, WT0, b0, nullptr, hm1, N_NODES_C);

    // ---- layer 1 ----
    mean_kernel<<<meanBlocks, 256, 0, stream>>>(hm1, offs, ssrc);
    sage_mfma<128, true, false><<<gemmBlocks, 256, 0, stream>>>(
        hm1, WT1, b1, nullptr, hm2, N_NODES_C);

    // ---- layer 2 ----
    mean_kernel<<<meanBlocks, 256, 0, stream>>>(hm2, offs, ssrc);
    sage_mfma<64, false, true><<<gemmBlocks, 256, 0, stream>>>(
        hm2, WT2, b2, out, nullptr, N_NODES_C);
}

// Round 4
// 301.424 us; speedup vs baseline: 1.8256x; 1.0486x over previous
//
#include <hip/hip_runtime.h>
#include <hip/hip_fp16.h>

#define N_NODES_C 50000
#define N_EDGES_C 800000
#define K_FEAT 128
#define HM_STRIDE 256  // [h(128) | mean(128)] fp16 per node

typedef unsigned int uint_t;
typedef _Float16 half8 __attribute__((ext_vector_type(8)));
typedef _Float16 half4 __attribute__((ext_vector_type(4)));
typedef float f32x4 __attribute__((ext_vector_type(4)));

// ---------------- CSR build ----------------

// 4 edges per thread (grid-stride), fire-and-forget atomics.
__global__ void count_kernel(const int* __restrict__ dst, int* __restrict__ cnt, int E) {
    const int S = gridDim.x * blockDim.x;
    int i = blockIdx.x * blockDim.x + threadIdx.x;
#pragma unroll
    for (int j = 0; j < 4; ++j) {
        int idx = i + j * S;
        if (idx < E) atomicAdd(&cnt[dst[idx]], 1);
    }
}

// Hierarchical scan, step 1: 256 threads x 4 elems = 1024/block.
__global__ void scan1_kernel(const int* __restrict__ cnt, int* __restrict__ offs,
                             int* __restrict__ bsums, int n) {
    const int t = threadIdx.x;
    const int lane = t & 63;
    const int wid = t >> 6;
    const int base = blockIdx.x * 1024 + t * 4;
    int v[4];
#pragma unroll
    for (int j = 0; j < 4; ++j) v[j] = (base + j < n) ? cnt[base + j] : 0;
    int s = v[0] + v[1] + v[2] + v[3];
    int x = s;
#pragma unroll
    for (int off = 1; off < 64; off <<= 1) {
        int y = __shfl_up(x, off, 64);
        if (lane >= off) x += y;
    }
    __shared__ int wsum[4];
    if (lane == 63) wsum[wid] = x;
    __syncthreads();
    int wpre = 0;
#pragma unroll
    for (int w = 0; w < 4; ++w)
        if (w < wid) wpre += wsum[w];
    int run = wpre + x - s;
#pragma unroll
    for (int j = 0; j < 4; ++j) {
        if (base + j < n) offs[base + j] = run;
        run += v[j];
    }
    if (t == 255) bsums[blockIdx.x] = wpre + x;
}

__global__ void scan2_kernel(int* __restrict__ bsums, int nb) {
    const int lane = threadIdx.x;
    int v = (lane < nb) ? bsums[lane] : 0;
    int x = v;
#pragma unroll
    for (int off = 1; off < 64; off <<= 1) {
        int y = __shfl_up(x, off, 64);
        if (lane >= off) x += y;
    }
    if (lane < nb) bsums[lane] = x - v;
}

__global__ void scan3_kernel(int* __restrict__ offs, int* __restrict__ cursor,
                             const int* __restrict__ bsums, int n, int total) {
    const int t = threadIdx.x;
    const int base = blockIdx.x * 1024 + t * 4;
    const int add = bsums[blockIdx.x];
#pragma unroll
    for (int j = 0; j < 4; ++j) {
        int idx = base + j;
        if (idx < n) {
            int o = offs[idx] + add;
            offs[idx] = o;
            cursor[idx] = o;
        }
    }
    if (blockIdx.x == 0 && t == 0) offs[n] = total;
}

// 4 edges per thread; all 4 atomic round-trips issued before dependent stores.
__global__ void fill_kernel(const int* __restrict__ src, const int* __restrict__ dst,
                            int* __restrict__ cursor, int* __restrict__ ssrc, int E) {
    const int S = gridDim.x * blockDim.x;
    const int i = blockIdx.x * blockDim.x + threadIdx.x;
    int idx[4], s[4], d[4];
    bool ok[4];
#pragma unroll
    for (int j = 0; j < 4; ++j) {
        idx[j] = i + j * S;
        ok[j] = idx[j] < E;
        s[j] = ok[j] ? src[idx[j]] : 0;
        d[j] = ok[j] ? dst[idx[j]] : 0;
    }
    int p[4];
#pragma unroll
    for (int j = 0; j < 4; ++j) p[j] = ok[j] ? atomicAdd(&cursor[d[j]], 1) : 0;
#pragma unroll
    for (int j = 0; j < 4; ++j)
        if (ok[j]) ssrc[p[j]] = s[j];
}

// ---------------- fp32 features -> fp16 h-part of hm0 ----------------

__global__ void f2h_kernel(const float* __restrict__ in, _Float16* __restrict__ hm, int n4) {
    int i = blockIdx.x * blockDim.x + threadIdx.x;
    if (i < n4) {
        float4 v = reinterpret_cast<const float4*>(in)[i];
        int n = i >> 5, c4 = i & 31;  // 32 float4 per 128-col row
        half4 o;
        o.x = (_Float16)v.x; o.y = (_Float16)v.y; o.z = (_Float16)v.z; o.w = (_Float16)v.w;
        *reinterpret_cast<half4*>(hm + (size_t)n * HM_STRIDE + c4 * 4) = o;
    }
}

// ---------------- weight convert+transpose: WT[c][k] = Wcat[k][c], fp16 ----------------

__global__ void wconv_kernel(const float* __restrict__ Ws, const float* __restrict__ Wn,
                             _Float16* __restrict__ WT, int ncol) {
    int idx = blockIdx.x * blockDim.x + threadIdx.x;
    if (idx >= ncol * 256) return;
    int k = idx & 255, c = idx >> 8;
    float v = (k < 128) ? Ws[(size_t)k * ncol + c] : Wn[(size_t)(k - 128) * ncol + c];
    WT[idx] = (_Float16)v;
}

// ---------------- mean aggregation: one wave per node, 8-deep MLP ----------------
// Reads h-part (cols 0..127) of hm, writes mean-part (cols 128..255).
// Lane loads one u32 (2 fp16) per edge-row; 8 independent loads in flight.

__global__ void mean_kernel(_Float16* __restrict__ hm, const int* __restrict__ offs,
                            const int* __restrict__ ssrc) {
    const int node = (int)((blockIdx.x * blockDim.x + threadIdx.x) >> 6);
    const int lane = threadIdx.x & 63;
    if (node >= N_NODES_C) return;
    const int beg = offs[node], end = offs[node + 1];
    const _Float16* base = hm + lane * 2;
    float a0[4] = {0.f, 0.f, 0.f, 0.f};
    float a1[4] = {0.f, 0.f, 0.f, 0.f};
    int e = beg;
    for (; e + 8 <= end; e += 8) {
        int sx[8];
#pragma unroll
        for (int j = 0; j < 8; ++j) sx[j] = ssrc[e + j];
        float2 v[8];
#pragma unroll
        for (int j = 0; j < 8; ++j)
            v[j] = __half22float2(*reinterpret_cast<const __half2*>(base + (size_t)sx[j] * HM_STRIDE));
#pragma unroll
        for (int j = 0; j < 8; ++j) {
            a0[j & 3] += v[j].x;
            a1[j & 3] += v[j].y;
        }
    }
    for (; e + 2 <= end; e += 2) {
        int s0 = ssrc[e], s1 = ssrc[e + 1];
        float2 v0 = __half22float2(*reinterpret_cast<const __half2*>(base + (size_t)s0 * HM_STRIDE));
        float2 v1 = __half22float2(*reinterpret_cast<const __half2*>(base + (size_t)s1 * HM_STRIDE));
        a0[0] += v0.x; a1[0] += v0.y;
        a0[1] += v1.x; a1[1] += v1.y;
    }
    if (e < end) {
        int s0 = ssrc[e];
        float2 v0 = __half22float2(*reinterpret_cast<const __half2*>(base + (size_t)s0 * HM_STRIDE));
        a0[2] += v0.x; a1[2] += v0.y;
    }
    const float inv = (end > beg) ? 1.0f / (float)(end - beg) : 0.f;
    float2 m;
    m.x = ((a0[0] + a0[1]) + (a0[2] + a0[3])) * inv;
    m.y = ((a1[0] + a1[1]) + (a1[2] + a1[3])) * inv;
    *reinterpret_cast<__half2*>(hm + (size_t)node * HM_STRIDE + 128 + lane * 2) =
        __float22half2_rn(m);
}

// ---------------- MFMA GEMM: out = act(hm @ Wcat + b), K=256 ----------------
// Block: 256 threads (4 waves), 64 rows x NCOL. Wave w owns rows [w*16, w*16+16).
// No LDS: A-frags straight from global; B-frags from WT (L2-hot).
// mfma_f32_16x16x32_f16, fp32 accum. C/D: col=lane&15, row=(lane>>4)*4+reg.

template <int NCOL, bool ACT, bool OUT_FP32>
__global__ __launch_bounds__(256) void sage_mfma(
    const _Float16* __restrict__ hm,  // [n][256]
    const _Float16* __restrict__ WT,  // [NCOL][256]
    const float* __restrict__ bias,
    float* __restrict__ outf,         // OUT_FP32: [n][NCOL]
    _Float16* __restrict__ outh,      // else: next layer's hm, h-part
    int nNodes) {
    constexpr int CF = NCOL / 16;  // col frags: 8 or 4
    const int wid = threadIdx.x >> 6;
    const int lane = threadIdx.x & 63;
    const int r0 = blockIdx.x * 64 + wid * 16;
    const int arow = r0 + (lane & 15);
    const int arow_c = (arow < nNodes) ? arow : 0;
    const int koff = (lane >> 4) * 8;

    const _Float16* aptr = hm + (size_t)arow_c * HM_STRIDE + koff;
    const _Float16* bbase = WT + (size_t)(lane & 15) * 256 + koff;

    f32x4 acc[CF];
#pragma unroll
    for (int c = 0; c < CF; ++c) acc[c] = {0.f, 0.f, 0.f, 0.f};

#pragma unroll
    for (int ks = 0; ks < 8; ++ks) {
        half8 a = *reinterpret_cast<const half8*>(aptr + ks * 32);
#pragma unroll
        for (int c = 0; c < CF; ++c) {
            half8 b = *reinterpret_cast<const half8*>(bbase + (size_t)c * 16 * 256 + ks * 32);
            acc[c] = __builtin_amdgcn_mfma_f32_16x16x32_f16(a, b, acc[c], 0, 0, 0);
        }
    }

    const int orow_base = r0 + ((lane >> 4) << 2);
    const int ocol = lane & 15;
#pragma unroll
    for (int c = 0; c < CF; ++c) {
        const int col = c * 16 + ocol;
        const float bv = bias[col];
#pragma unroll
        for (int reg = 0; reg < 4; ++reg) {
            const int row = orow_base + reg;
            if (row < nNodes) {
                float v = acc[c][reg] + bv;
                if (ACT) v = fmaxf(v, 0.f);
                if (OUT_FP32) outf[(size_t)row * NCOL + col] = v;
                else outh[(size_t)row * HM_STRIDE + col] = (_Float16)v;
            }
        }
    }
}

// ---------------- launch ----------------

extern "C" void kernel_launch(void* const* d_in, const int* in_sizes, int n_in,
                              void* d_out, int out_size, void* d_ws, size_t ws_size,
                              hipStream_t stream) {
    const float* feat = (const float*)d_in[0];
    const int* src = (const int*)d_in[1];
    const int* dst = (const int*)d_in[2];
    const float* Ws0 = (const float*)d_in[3];
    const float* Wn0 = (const float*)d_in[4];
    const float* b0 = (const float*)d_in[5];
    const float* Ws1 = (const float*)d_in[6];
    const float* Wn1 = (const float*)d_in[7];
    const float* b1 = (const float*)d_in[8];
    const float* Ws2 = (const float*)d_in[9];
    const float* Wn2 = (const float*)d_in[10];
    const float* b2 = (const float*)d_in[11];
    float* out = (float*)d_out;

    auto align_up = [](size_t x) { return (x + 255) & ~(size_t)255; };
    char* w = (char*)d_ws;
    int* cursor = (int*)w;  w += align_up((size_t)N_NODES_C * 4);
    int* offs = (int*)w;    w += align_up((size_t)(N_NODES_C + 1) * 4);
    int* bsums = (int*)w;   w += align_up(64 * 4);
    int* ssrc = (int*)w;    w += align_up((size_t)N_EDGES_C * 4);
    _Float16* hm0 = (_Float16*)w; w += align_up((size_t)N_NODES_C * HM_STRIDE * 2);
    _Float16* hm1 = (_Float16*)w; w += align_up((size_t)N_NODES_C * HM_STRIDE * 2);
    _Float16* WT0 = (_Float16*)w; w += align_up((size_t)128 * 256 * 2);
    _Float16* WT1 = (_Float16*)w; w += align_up((size_t)128 * 256 * 2);
    _Float16* WT2 = (_Float16*)w; w += align_up((size_t)64 * 256 * 2);
    _Float16* hm2 = hm0;  // hm0 is dead after GEMM0 reads it

    const int scanBlocks = (N_NODES_C + 1023) / 1024;  // 49
    const int edge4Blocks = (N_EDGES_C + 1023) / 1024; // 782 (4 edges/thread)

    // ---- CSR build ----
    hipMemsetAsync(cursor, 0, (size_t)N_NODES_C * 4, stream);
    count_kernel<<<edge4Blocks, 256, 0, stream>>>(dst, cursor, N_EDGES_C);
    scan1_kernel<<<scanBlocks, 256, 0, stream>>>(cursor, offs, bsums, N_NODES_C);
    scan2_kernel<<<1, 64, 0, stream>>>(bsums, scanBlocks);
    scan3_kernel<<<scanBlocks, 256, 0, stream>>>(offs, cursor, bsums, N_NODES_C, N_EDGES_C);
    fill_kernel<<<edge4Blocks, 256, 0, stream>>>(src, dst, cursor, ssrc, N_EDGES_C);

    // ---- features -> fp16 into hm0 h-part; weights -> fp16 transposed ----
    const int n4 = N_NODES_C * K_FEAT / 4;
    f2h_kernel<<<(n4 + 255) / 256, 256, 0, stream>>>(feat, hm0, n4);
    wconv_kernel<<<(128 * 256 + 255) / 256, 256, 0, stream>>>(Ws0, Wn0, WT0, 128);
    wconv_kernel<<<(128 * 256 + 255) / 256, 256, 0, stream>>>(Ws1, Wn1, WT1, 128);
    wconv_kernel<<<(64 * 256 + 255) / 256, 256, 0, stream>>>(Ws2, Wn2, WT2, 64);

    const int meanBlocks = (N_NODES_C * 64 + 255) / 256;
    const int gemmBlocks = (N_NODES_C + 63) / 64;  // 782

    // ---- layer 0 ----
    mean_kernel<<<meanBlocks, 256, 0, stream>>>(hm0, offs, ssrc);
    sage_mfma<128, true, false><<<gemmBlocks, 256, 0, stream>>>(
        hm0, WT0, b0, nullptr, hm1, N_NODES_C);

    // ---- layer 1 ----
    mean_kernel<<<meanBlocks, 256, 0, stream>>>(hm1, offs, ssrc);
    sage_mfma<128, true, false><<<gemmBlocks, 256, 0, stream>>>(
        hm1, WT1, b1, nullptr, hm2, N_NODES_C);

    // ---- layer 2 ----
    mean_kernel<<<meanBlocks, 256, 0, stream>>>(hm2, offs, ssrc);
    sage_mfma<64, false, true><<<gemmBlocks, 256, 0, stream>>>(
        hm2, WT2, b2, out, nullptr, N_NODES_C);
}

// Round 5
// 267.002 us; speedup vs baseline: 2.0610x; 1.1289x over previous
//
#include <hip/hip_runtime.h>
#include <hip/hip_fp16.h>

#define N_NODES_C 50000
#define N_EDGES_C 800000
#define K_FEAT 128
#define HM_STRIDE 256  // [h(128) | mean(128)] fp16 per node

typedef unsigned int uint_t;
typedef _Float16 half8 __attribute__((ext_vector_type(8)));
typedef _Float16 half4 __attribute__((ext_vector_type(4)));
typedef float f32x4 __attribute__((ext_vector_type(4)));

// ---------------- CSR build ----------------

// Counting atomic doubles as rank assignment: rank[i] = #earlier edges with same dst.
// rank store is coalesced (edge-ordered).
__global__ void count_rank_kernel(const int* __restrict__ dst, int* __restrict__ cnt,
                                  int* __restrict__ rank, int E) {
    int i = blockIdx.x * blockDim.x + threadIdx.x;
    if (i < E) rank[i] = atomicAdd(&cnt[dst[i]], 1);
}

// Hierarchical scan, step 1: 256 threads x 4 elems = 1024/block.
__global__ void scan1_kernel(const int* __restrict__ cnt, int* __restrict__ offs,
                             int* __restrict__ bsums, int n) {
    const int t = threadIdx.x;
    const int lane = t & 63;
    const int wid = t >> 6;
    const int base = blockIdx.x * 1024 + t * 4;
    int v[4];
#pragma unroll
    for (int j = 0; j < 4; ++j) v[j] = (base + j < n) ? cnt[base + j] : 0;
    int s = v[0] + v[1] + v[2] + v[3];
    int x = s;
#pragma unroll
    for (int off = 1; off < 64; off <<= 1) {
        int y = __shfl_up(x, off, 64);
        if (lane >= off) x += y;
    }
    __shared__ int wsum[4];
    if (lane == 63) wsum[wid] = x;
    __syncthreads();
    int wpre = 0;
#pragma unroll
    for (int w = 0; w < 4; ++w)
        if (w < wid) wpre += wsum[w];
    int run = wpre + x - s;
#pragma unroll
    for (int j = 0; j < 4; ++j) {
        if (base + j < n) offs[base + j] = run;
        run += v[j];
    }
    if (t == 255) bsums[blockIdx.x] = wpre + x;
}

__global__ void scan2_kernel(int* __restrict__ bsums, int nb) {
    const int lane = threadIdx.x;
    int v = (lane < nb) ? bsums[lane] : 0;
    int x = v;
#pragma unroll
    for (int off = 1; off < 64; off <<= 1) {
        int y = __shfl_up(x, off, 64);
        if (lane >= off) x += y;
    }
    if (lane < nb) bsums[lane] = x - v;
}

__global__ void scan3_kernel(int* __restrict__ offs, const int* __restrict__ bsums,
                             int n, int total) {
    const int t = threadIdx.x;
    const int base = blockIdx.x * 1024 + t * 4;
    const int add = bsums[blockIdx.x];
#pragma unroll
    for (int j = 0; j < 4; ++j) {
        int idx = base + j;
        if (idx < n) offs[idx] += add;
    }
    if (blockIdx.x == 0 && t == 0) offs[n] = total;
}

// Atomic-free fill: ssrc[offs[dst] + rank] = src. 4 edges/thread, independent chains.
__global__ void fill_kernel(const int* __restrict__ src, const int* __restrict__ dst,
                            const int* __restrict__ rank, const int* __restrict__ offs,
                            int* __restrict__ ssrc, int E) {
    const int i = (blockIdx.x * blockDim.x + threadIdx.x) * 4;
    if (i + 4 <= E) {
        int4 s = *reinterpret_cast<const int4*>(src + i);
        int4 d = *reinterpret_cast<const int4*>(dst + i);
        int4 r = *reinterpret_cast<const int4*>(rank + i);
        int o0 = offs[d.x], o1 = offs[d.y], o2 = offs[d.z], o3 = offs[d.w];
        ssrc[o0 + r.x] = s.x;
        ssrc[o1 + r.y] = s.y;
        ssrc[o2 + r.z] = s.z;
        ssrc[o3 + r.w] = s.w;
    } else {
        for (int j = i; j < E; ++j) ssrc[offs[dst[j]] + rank[j]] = src[j];
    }
}

// ---------------- fp32 features -> fp16 h-part of hm0 ----------------

__global__ void f2h_kernel(const float* __restrict__ in, _Float16* __restrict__ hm, int n4) {
    int i = blockIdx.x * blockDim.x + threadIdx.x;
    if (i < n4) {
        float4 v = reinterpret_cast<const float4*>(in)[i];
        int n = i >> 5, c4 = i & 31;  // 32 float4 per 128-col row
        half4 o;
        o.x = (_Float16)v.x; o.y = (_Float16)v.y; o.z = (_Float16)v.z; o.w = (_Float16)v.w;
        *reinterpret_cast<half4*>(hm + (size_t)n * HM_STRIDE + c4 * 4) = o;
    }
}

// ---------------- weight convert+transpose, all 3 layers in one launch ----------------
// WT[c][k] = Wcat[k][c] fp16; Wcat rows 0..127 = Ws, 128..255 = Wn.

__global__ void wconv_all_kernel(const float* __restrict__ Ws0, const float* __restrict__ Wn0,
                                 const float* __restrict__ Ws1, const float* __restrict__ Wn1,
                                 const float* __restrict__ Ws2, const float* __restrict__ Wn2,
                                 _Float16* __restrict__ WT0, _Float16* __restrict__ WT1,
                                 _Float16* __restrict__ WT2) {
    int idx = blockIdx.x * blockDim.x + threadIdx.x;
    const float* Ws;
    const float* Wn;
    _Float16* WT;
    int ncol;
    if (idx < 32768) { Ws = Ws0; Wn = Wn0; WT = WT0; ncol = 128; }
    else if (idx < 65536) { idx -= 32768; Ws = Ws1; Wn = Wn1; WT = WT1; ncol = 128; }
    else if (idx < 81920) { idx -= 65536; Ws = Ws2; Wn = Wn2; WT = WT2; ncol = 64; }
    else return;
    int k = idx & 255, c = idx >> 8;
    float v = (k < 128) ? Ws[(size_t)k * ncol + c] : Wn[(size_t)(k - 128) * ncol + c];
    WT[(size_t)c * 256 + k] = (_Float16)v;
}

// ---------------- mean aggregation: one wave per node, 8-deep MLP ----------------

__global__ void mean_kernel(_Float16* __restrict__ hm, const int* __restrict__ offs,
                            const int* __restrict__ ssrc) {
    const int node = (int)((blockIdx.x * blockDim.x + threadIdx.x) >> 6);
    const int lane = threadIdx.x & 63;
    if (node >= N_NODES_C) return;
    const int beg = offs[node], end = offs[node + 1];
    const _Float16* base = hm + lane * 2;
    float a0[4] = {0.f, 0.f, 0.f, 0.f};
    float a1[4] = {0.f, 0.f, 0.f, 0.f};
    int e = beg;
    for (; e + 8 <= end; e += 8) {
        int sx[8];
#pragma unroll
        for (int j = 0; j < 8; ++j) sx[j] = ssrc[e + j];
        float2 v[8];
#pragma unroll
        for (int j = 0; j < 8; ++j)
            v[j] = __half22float2(*reinterpret_cast<const __half2*>(base + (size_t)sx[j] * HM_STRIDE));
#pragma unroll
        for (int j = 0; j < 8; ++j) {
            a0[j & 3] += v[j].x;
            a1[j & 3] += v[j].y;
        }
    }
    for (; e + 2 <= end; e += 2) {
        int s0 = ssrc[e], s1 = ssrc[e + 1];
        float2 v0 = __half22float2(*reinterpret_cast<const __half2*>(base + (size_t)s0 * HM_STRIDE));
        float2 v1 = __half22float2(*reinterpret_cast<const __half2*>(base + (size_t)s1 * HM_STRIDE));
        a0[0] += v0.x; a1[0] += v0.y;
        a0[1] += v1.x; a1[1] += v1.y;
    }
    if (e < end) {
        int s0 = ssrc[e];
        float2 v0 = __half22float2(*reinterpret_cast<const __half2*>(base + (size_t)s0 * HM_STRIDE));
        a0[2] += v0.x; a1[2] += v0.y;
    }
    const float inv = (end > beg) ? 1.0f / (float)(end - beg) : 0.f;
    float2 m;
    m.x = ((a0[0] + a0[1]) + (a0[2] + a0[3])) * inv;
    m.y = ((a1[0] + a1[1]) + (a1[2] + a1[3])) * inv;
    *reinterpret_cast<__half2*>(hm + (size_t)node * HM_STRIDE + 128 + lane * 2) =
        __float22half2_rn(m);
}

// ---------------- MFMA GEMM: out = act(hm @ Wcat + b), K=256 ----------------
// Block: 256 threads (4 waves), 64 rows x NCOL. No LDS: A-frags from global,
// B-frags from WT (L2-hot). mfma_f32_16x16x32_f16, fp32 accum.
// C/D: col=lane&15, row=(lane>>4)*4+reg (m89-verified mapping).

template <int NCOL, bool ACT, bool OUT_FP32>
__global__ __launch_bounds__(256) void sage_mfma(
    const _Float16* __restrict__ hm,  // [n][256]
    const _Float16* __restrict__ WT,  // [NCOL][256]
    const float* __restrict__ bias,
    float* __restrict__ outf,         // OUT_FP32: [n][NCOL]
    _Float16* __restrict__ outh,      // else: next layer's hm, h-part
    int nNodes) {
    constexpr int CF = NCOL / 16;  // col frags: 8 or 4
    const int wid = threadIdx.x >> 6;
    const int lane = threadIdx.x & 63;
    const int r0 = blockIdx.x * 64 + wid * 16;
    const int arow = r0 + (lane & 15);
    const int arow_c = (arow < nNodes) ? arow : 0;
    const int koff = (lane >> 4) * 8;

    const _Float16* aptr = hm + (size_t)arow_c * HM_STRIDE + koff;
    const _Float16* bbase = WT + (size_t)(lane & 15) * 256 + koff;

    f32x4 acc[CF];
#pragma unroll
    for (int c = 0; c < CF; ++c) acc[c] = {0.f, 0.f, 0.f, 0.f};

#pragma unroll
    for (int ks = 0; ks < 8; ++ks) {
        half8 a = *reinterpret_cast<const half8*>(aptr + ks * 32);
#pragma unroll
        for (int c = 0; c < CF; ++c) {
            half8 b = *reinterpret_cast<const half8*>(bbase + (size_t)c * 16 * 256 + ks * 32);
            acc[c] = __builtin_amdgcn_mfma_f32_16x16x32_f16(a, b, acc[c], 0, 0, 0);
        }
    }

    const int orow_base = r0 + ((lane >> 4) << 2);
    const int ocol = lane & 15;
#pragma unroll
    for (int c = 0; c < CF; ++c) {
        const int col = c * 16 + ocol;
        const float bv = bias[col];
#pragma unroll
        for (int reg = 0; reg < 4; ++reg) {
            const int row = orow_base + reg;
            if (row < nNodes) {
                float v = acc[c][reg] + bv;
                if (ACT) v = fmaxf(v, 0.f);
                if (OUT_FP32) outf[(size_t)row * NCOL + col] = v;
                else outh[(size_t)row * HM_STRIDE + col] = (_Float16)v;
            }
        }
    }
}

// ---------------- launch ----------------

extern "C" void kernel_launch(void* const* d_in, const int* in_sizes, int n_in,
                              void* d_out, int out_size, void* d_ws, size_t ws_size,
                              hipStream_t stream) {
    const float* feat = (const float*)d_in[0];
    const int* src = (const int*)d_in[1];
    const int* dst = (const int*)d_in[2];
    const float* Ws0 = (const float*)d_in[3];
    const float* Wn0 = (const float*)d_in[4];
    const float* b0 = (const float*)d_in[5];
    const float* Ws1 = (const float*)d_in[6];
    const float* Wn1 = (const float*)d_in[7];
    const float* b1 = (const float*)d_in[8];
    const float* Ws2 = (const float*)d_in[9];
    const float* Wn2 = (const float*)d_in[10];
    const float* b2 = (const float*)d_in[11];
    float* out = (float*)d_out;

    auto align_up = [](size_t x) { return (x + 255) & ~(size_t)255; };
    char* w = (char*)d_ws;
    int* cnt = (int*)w;     w += align_up((size_t)N_NODES_C * 4);
    int* offs = (int*)w;    w += align_up((size_t)(N_NODES_C + 1) * 4);
    int* bsums = (int*)w;   w += align_up(64 * 4);
    int* rank = (int*)w;    w += align_up((size_t)N_EDGES_C * 4);
    int* ssrc = (int*)w;    w += align_up((size_t)N_EDGES_C * 4);
    _Float16* hm0 = (_Float16*)w; w += align_up((size_t)N_NODES_C * HM_STRIDE * 2);
    _Float16* hm1 = (_Float16*)w; w += align_up((size_t)N_NODES_C * HM_STRIDE * 2);
    _Float16* WT0 = (_Float16*)w; w += align_up((size_t)128 * 256 * 2);
    _Float16* WT1 = (_Float16*)w; w += align_up((size_t)128 * 256 * 2);
    _Float16* WT2 = (_Float16*)w; w += align_up((size_t)64 * 256 * 2);
    _Float16* hm2 = hm0;  // hm0 is dead after GEMM0 reads it

    const int scanBlocks = (N_NODES_C + 1023) / 1024;  // 49
    const int edgeBlocks = (N_EDGES_C + 255) / 256;    // 3125 (1 edge/thread)
    const int edge4Blocks = (N_EDGES_C / 4 + 255) / 256;  // 782 (4 edges/thread)

    // ---- CSR build ----
    hipMemsetAsync(cnt, 0, (size_t)N_NODES_C * 4, stream);
    count_rank_kernel<<<edgeBlocks, 256, 0, stream>>>(dst, cnt, rank, N_EDGES_C);
    scan1_kernel<<<scanBlocks, 256, 0, stream>>>(cnt, offs, bsums, N_NODES_C);
    scan2_kernel<<<1, 64, 0, stream>>>(bsums, scanBlocks);
    scan3_kernel<<<scanBlocks, 256, 0, stream>>>(offs, bsums, N_NODES_C, N_EDGES_C);
    fill_kernel<<<edge4Blocks, 256, 0, stream>>>(src, dst, rank, offs, ssrc, N_EDGES_C);

    // ---- features -> fp16 into hm0 h-part; weights -> fp16 transposed ----
    const int n4 = N_NODES_C * K_FEAT / 4;
    f2h_kernel<<<(n4 + 255) / 256, 256, 0, stream>>>(feat, hm0, n4);
    wconv_all_kernel<<<(81920 + 255) / 256, 256, 0, stream>>>(
        Ws0, Wn0, Ws1, Wn1, Ws2, Wn2, WT0, WT1, WT2);

    const int meanBlocks = (N_NODES_C * 64 + 255) / 256;
    const int gemmBlocks = (N_NODES_C + 63) / 64;  // 782

    // ---- layer 0 ----
    mean_kernel<<<meanBlocks, 256, 0, stream>>>(hm0, offs, ssrc);
    sage_mfma<128, true, false><<<gemmBlocks, 256, 0, stream>>>(
        hm0, WT0, b0, nullptr, hm1, N_NODES_C);

    // ---- layer 1 ----
    mean_kernel<<<meanBlocks, 256, 0, stream>>>(hm1, offs, ssrc);
    sage_mfma<128, true, false><<<gemmBlocks, 256, 0, stream>>>(
        hm1, WT1, b1, nullptr, hm2, N_NODES_C);

    // ---- layer 2 ----
    mean_kernel<<<meanBlocks, 256, 0, stream>>>(hm2, offs, ssrc);
    sage_mfma<64, false, true><<<gemmBlocks, 256, 0, stream>>>(
        hm2, WT2, b2, out, nullptr, N_NODES_C);
}

// Round 6
// 208.664 us; speedup vs baseline: 2.6372x; 1.2796x over previous
//
#include <hip/hip_runtime.h>
#include <hip/hip_fp16.h>

#define N_NODES_C 50000
#define N_EDGES_C 800000
#define K_FEAT 128
#define HM_STRIDE 256  // [h(128) | mean(128)] fp16 per node

typedef unsigned int uint_t;
typedef _Float16 half8 __attribute__((ext_vector_type(8)));
typedef _Float16 half4 __attribute__((ext_vector_type(4)));
typedef float f32x4 __attribute__((ext_vector_type(4)));

// ---------------- CSR build ----------------

// Counting atomic doubles as rank assignment: rank[i] = #earlier edges with same dst.
__global__ void count_rank_kernel(const int* __restrict__ dst, int* __restrict__ cnt,
                                  int* __restrict__ rank, int E) {
    int i = blockIdx.x * blockDim.x + threadIdx.x;
    if (i < E) rank[i] = atomicAdd(&cnt[dst[i]], 1);
}

// Hierarchical scan, step 1: 256 threads x 4 elems = 1024/block.
__global__ void scan1_kernel(const int* __restrict__ cnt, int* __restrict__ offs,
                             int* __restrict__ bsums, int n) {
    const int t = threadIdx.x;
    const int lane = t & 63;
    const int wid = t >> 6;
    const int base = blockIdx.x * 1024 + t * 4;
    int v[4];
#pragma unroll
    for (int j = 0; j < 4; ++j) v[j] = (base + j < n) ? cnt[base + j] : 0;
    int s = v[0] + v[1] + v[2] + v[3];
    int x = s;
#pragma unroll
    for (int off = 1; off < 64; off <<= 1) {
        int y = __shfl_up(x, off, 64);
        if (lane >= off) x += y;
    }
    __shared__ int wsum[4];
    if (lane == 63) wsum[wid] = x;
    __syncthreads();
    int wpre = 0;
#pragma unroll
    for (int w = 0; w < 4; ++w)
        if (w < wid) wpre += wsum[w];
    int run = wpre + x - s;
#pragma unroll
    for (int j = 0; j < 4; ++j) {
        if (base + j < n) offs[base + j] = run;
        run += v[j];
    }
    if (t == 255) bsums[blockIdx.x] = wpre + x;
}

__global__ void scan2_kernel(int* __restrict__ bsums, int nb) {
    const int lane = threadIdx.x;
    int v = (lane < nb) ? bsums[lane] : 0;
    int x = v;
#pragma unroll
    for (int off = 1; off < 64; off <<= 1) {
        int y = __shfl_up(x, off, 64);
        if (lane >= off) x += y;
    }
    if (lane < nb) bsums[lane] = x - v;
}

__global__ void scan3_kernel(int* __restrict__ offs, const int* __restrict__ bsums,
                             int n, int total) {
    const int t = threadIdx.x;
    const int base = blockIdx.x * 1024 + t * 4;
    const int add = bsums[blockIdx.x];
#pragma unroll
    for (int j = 0; j < 4; ++j) {
        int idx = base + j;
        if (idx < n) offs[idx] += add;
    }
    if (blockIdx.x == 0 && t == 0) offs[n] = total;
}

// Atomic-free fill: ssrc[offs[dst] + rank] = src. 4 edges/thread, independent chains.
__global__ void fill_kernel(const int* __restrict__ src, const int* __restrict__ dst,
                            const int* __restrict__ rank, const int* __restrict__ offs,
                            int* __restrict__ ssrc, int E) {
    const int i = (blockIdx.x * blockDim.x + threadIdx.x) * 4;
    if (i + 4 <= E) {
        int4 s = *reinterpret_cast<const int4*>(src + i);
        int4 d = *reinterpret_cast<const int4*>(dst + i);
        int4 r = *reinterpret_cast<const int4*>(rank + i);
        int o0 = offs[d.x], o1 = offs[d.y], o2 = offs[d.z], o3 = offs[d.w];
        ssrc[o0 + r.x] = s.x;
        ssrc[o1 + r.y] = s.y;
        ssrc[o2 + r.z] = s.z;
        ssrc[o3 + r.w] = s.w;
    } else {
        for (int j = i; j < E; ++j) ssrc[offs[dst[j]] + rank[j]] = src[j];
    }
}

// ---------------- fp32 features -> fp16 h-part of hm0 ----------------

__global__ void f2h_kernel(const float* __restrict__ in, _Float16* __restrict__ hm, int n4) {
    int i = blockIdx.x * blockDim.x + threadIdx.x;
    if (i < n4) {
        float4 v = reinterpret_cast<const float4*>(in)[i];
        int n = i >> 5, c4 = i & 31;  // 32 float4 per 128-col row
        half4 o;
        o.x = (_Float16)v.x; o.y = (_Float16)v.y; o.z = (_Float16)v.z; o.w = (_Float16)v.w;
        *reinterpret_cast<half4*>(hm + (size_t)n * HM_STRIDE + c4 * 4) = o;
    }
}

// ---------------- weight convert+transpose, all 3 layers in one launch ----------------
// WT[c][k] = Wcat[k][c] fp16; Wcat rows 0..127 = Ws, 128..255 = Wn.

__global__ void wconv_all_kernel(const float* __restrict__ Ws0, const float* __restrict__ Wn0,
                                 const float* __restrict__ Ws1, const float* __restrict__ Wn1,
                                 const float* __restrict__ Ws2, const float* __restrict__ Wn2,
                                 _Float16* __restrict__ WT0, _Float16* __restrict__ WT1,
                                 _Float16* __restrict__ WT2) {
    int idx = blockIdx.x * blockDim.x + threadIdx.x;
    const float* Ws;
    const float* Wn;
    _Float16* WT;
    int ncol;
    if (idx < 32768) { Ws = Ws0; Wn = Wn0; WT = WT0; ncol = 128; }
    else if (idx < 65536) { idx -= 32768; Ws = Ws1; Wn = Wn1; WT = WT1; ncol = 128; }
    else if (idx < 81920) { idx -= 65536; Ws = Ws2; Wn = Wn2; WT = WT2; ncol = 64; }
    else return;
    int k = idx & 255, c = idx >> 8;
    float v = (k < 128) ? Ws[(size_t)k * ncol + c] : Wn[(size_t)(k - 128) * ncol + c];
    WT[(size_t)c * 256 + k] = (_Float16)v;
}

// ---------------- mean aggregation: one wave per node, 8-deep MLP ----------------

__global__ void mean_kernel(_Float16* __restrict__ hm, const int* __restrict__ offs,
                            const int* __restrict__ ssrc) {
    const int node = (int)((blockIdx.x * blockDim.x + threadIdx.x) >> 6);
    const int lane = threadIdx.x & 63;
    if (node >= N_NODES_C) return;
    const int beg = offs[node], end = offs[node + 1];
    const _Float16* base = hm + lane * 2;
    float a0[4] = {0.f, 0.f, 0.f, 0.f};
    float a1[4] = {0.f, 0.f, 0.f, 0.f};
    int e = beg;
    for (; e + 8 <= end; e += 8) {
        int sx[8];
#pragma unroll
        for (int j = 0; j < 8; ++j) sx[j] = ssrc[e + j];
        float2 v[8];
#pragma unroll
        for (int j = 0; j < 8; ++j)
            v[j] = __half22float2(*reinterpret_cast<const __half2*>(base + (size_t)sx[j] * HM_STRIDE));
#pragma unroll
        for (int j = 0; j < 8; ++j) {
            a0[j & 3] += v[j].x;
            a1[j & 3] += v[j].y;
        }
    }
    for (; e + 2 <= end; e += 2) {
        int s0 = ssrc[e], s1 = ssrc[e + 1];
        float2 v0 = __half22float2(*reinterpret_cast<const __half2*>(base + (size_t)s0 * HM_STRIDE));
        float2 v1 = __half22float2(*reinterpret_cast<const __half2*>(base + (size_t)s1 * HM_STRIDE));
        a0[0] += v0.x; a1[0] += v0.y;
        a0[1] += v1.x; a1[1] += v1.y;
    }
    if (e < end) {
        int s0 = ssrc[e];
        float2 v0 = __half22float2(*reinterpret_cast<const __half2*>(base + (size_t)s0 * HM_STRIDE));
        a0[2] += v0.x; a1[2] += v0.y;
    }
    const float inv = (end > beg) ? 1.0f / (float)(end - beg) : 0.f;
    float2 m;
    m.x = ((a0[0] + a0[1]) + (a0[2] + a0[3])) * inv;
    m.y = ((a1[0] + a1[1]) + (a1[2] + a1[3])) * inv;
    *reinterpret_cast<__half2*>(hm + (size_t)node * HM_STRIDE + 128 + lane * 2) =
        __float22half2_rn(m);
}

// ---------------- MFMA GEMM: out = act(hm @ Wcat + b), K=256 ----------------
// Block: 256 threads (4 waves), 128 rows (32/wave). WT staged in LDS (XOR-swizzled,
// exactly NCOL*512 bytes). All 16 A-frags preloaded to registers (independent global
// loads), then pure LDS+MFMA with 2*CF independent acc chains.
// Swizzle: half_col ^= (row&7)<<3 -> 8 rows hit 8 distinct 16B slots (2-way max, free).
// C/D mapping: col=lane&15, row=(lane>>4)*4+reg (m89-verified).

template <int NCOL, bool ACT, bool OUT_FP32>
__global__ __launch_bounds__(256) void sage_mfma(
    const _Float16* __restrict__ hm,  // [n][256]
    const _Float16* __restrict__ WT,  // [NCOL][256]
    const float* __restrict__ bias,
    float* __restrict__ outf,         // OUT_FP32: [n][NCOL]
    _Float16* __restrict__ outh,      // else: next layer's hm, h-part
    int nNodes) {
    constexpr int CF = NCOL / 16;  // col frags: 8 or 4
    constexpr int RPW = 32;        // rows per wave (2 row-frags)
    constexpr int RPB = 128;       // rows per block

    __shared__ _Float16 bl[NCOL][256];  // 64KB (NCOL=128) / 32KB (NCOL=64)

    const int t = threadIdx.x;
    // ---- stage WT into LDS, swizzled ----
#pragma unroll
    for (int it = 0; it < NCOL * 32 / 256; ++it) {
        int f = t + it * 256;
        int row = f >> 5, c8 = f & 31;
        half8 v = *reinterpret_cast<const half8*>(WT + (size_t)row * 256 + c8 * 8);
        int col = (c8 * 8) ^ ((row & 7) << 3);
        *reinterpret_cast<half8*>(&bl[row][col]) = v;
    }
    __syncthreads();

    const int wid = t >> 6;
    const int lane = t & 63;
    const int r0 = blockIdx.x * RPB + wid * RPW;
    const int koff = (lane >> 4) * 8;  // k sub-offset in halfs

    // ---- preload A: 2 row-frags x 8 k-steps, all independent ----
    half8 a[2][8];
#pragma unroll
    for (int fr = 0; fr < 2; ++fr) {
        int row = r0 + fr * 16 + (lane & 15);
        if (row >= nNodes) row = nNodes - 1;  // clamped; results discarded on store
        const _Float16* ap = hm + (size_t)row * HM_STRIDE + koff;
#pragma unroll
        for (int ks = 0; ks < 8; ++ks)
            a[fr][ks] = *reinterpret_cast<const half8*>(ap + ks * 32);
    }

    f32x4 acc[2][CF];
#pragma unroll
    for (int fr = 0; fr < 2; ++fr)
#pragma unroll
        for (int c = 0; c < CF; ++c) acc[fr][c] = {0.f, 0.f, 0.f, 0.f};

    // ---- main: LDS b-frags + MFMA ----
#pragma unroll
    for (int c = 0; c < CF; ++c) {
        const int brow = c * 16 + (lane & 15);
        const int bswz = (brow & 7) << 3;
#pragma unroll
        for (int ks = 0; ks < 8; ++ks) {
            half8 b = *reinterpret_cast<const half8*>(&bl[brow][(ks * 32 + koff) ^ bswz]);
            acc[0][c] = __builtin_amdgcn_mfma_f32_16x16x32_f16(a[0][ks], b, acc[0][c], 0, 0, 0);
            acc[1][c] = __builtin_amdgcn_mfma_f32_16x16x32_f16(a[1][ks], b, acc[1][c], 0, 0, 0);
        }
    }

    // ---- epilogue ----
    const int ocol = lane & 15;
    const int orow_off = (lane >> 4) << 2;
#pragma unroll
    for (int fr = 0; fr < 2; ++fr) {
        const int rbase = r0 + fr * 16 + orow_off;
#pragma unroll
        for (int c = 0; c < CF; ++c) {
            const int col = c * 16 + ocol;
            const float bv = bias[col];
#pragma unroll
            for (int reg = 0; reg < 4; ++reg) {
                const int row = rbase + reg;
                if (row < nNodes) {
                    float v = acc[fr][c][reg] + bv;
                    if (ACT) v = fmaxf(v, 0.f);
                    if (OUT_FP32) outf[(size_t)row * NCOL + col] = v;
                    else outh[(size_t)row * HM_STRIDE + col] = (_Float16)v;
                }
            }
        }
    }
}

// ---------------- launch ----------------

extern "C" void kernel_launch(void* const* d_in, const int* in_sizes, int n_in,
                              void* d_out, int out_size, void* d_ws, size_t ws_size,
                              hipStream_t stream) {
    const float* feat = (const float*)d_in[0];
    const int* src = (const int*)d_in[1];
    const int* dst = (const int*)d_in[2];
    const float* Ws0 = (const float*)d_in[3];
    const float* Wn0 = (const float*)d_in[4];
    const float* b0 = (const float*)d_in[5];
    const float* Ws1 = (const float*)d_in[6];
    const float* Wn1 = (const float*)d_in[7];
    const float* b1 = (const float*)d_in[8];
    const float* Ws2 = (const float*)d_in[9];
    const float* Wn2 = (const float*)d_in[10];
    const float* b2 = (const float*)d_in[11];
    float* out = (float*)d_out;

    auto align_up = [](size_t x) { return (x + 255) & ~(size_t)255; };
    char* w = (char*)d_ws;
    int* cnt = (int*)w;     w += align_up((size_t)N_NODES_C * 4);
    int* offs = (int*)w;    w += align_up((size_t)(N_NODES_C + 1) * 4);
    int* bsums = (int*)w;   w += align_up(64 * 4);
    int* rank = (int*)w;    w += align_up((size_t)N_EDGES_C * 4);
    int* ssrc = (int*)w;    w += align_up((size_t)N_EDGES_C * 4);
    _Float16* hm0 = (_Float16*)w; w += align_up((size_t)N_NODES_C * HM_STRIDE * 2);
    _Float16* hm1 = (_Float16*)w; w += align_up((size_t)N_NODES_C * HM_STRIDE * 2);
    _Float16* WT0 = (_Float16*)w; w += align_up((size_t)128 * 256 * 2);
    _Float16* WT1 = (_Float16*)w; w += align_up((size_t)128 * 256 * 2);
    _Float16* WT2 = (_Float16*)w; w += align_up((size_t)64 * 256 * 2);
    _Float16* hm2 = hm0;  // hm0 is dead after GEMM0 reads it

    const int scanBlocks = (N_NODES_C + 1023) / 1024;  // 49
    const int edgeBlocks = (N_EDGES_C + 255) / 256;    // 3125 (1 edge/thread)
    const int edge4Blocks = (N_EDGES_C / 4 + 255) / 256;  // 782 (4 edges/thread)

    // ---- CSR build ----
    hipMemsetAsync(cnt, 0, (size_t)N_NODES_C * 4, stream);
    count_rank_kernel<<<edgeBlocks, 256, 0, stream>>>(dst, cnt, rank, N_EDGES_C);
    scan1_kernel<<<scanBlocks, 256, 0, stream>>>(cnt, offs, bsums, N_NODES_C);
    scan2_kernel<<<1, 64, 0, stream>>>(bsums, scanBlocks);
    scan3_kernel<<<scanBlocks, 256, 0, stream>>>(offs, bsums, N_NODES_C, N_EDGES_C);
    fill_kernel<<<edge4Blocks, 256, 0, stream>>>(src, dst, rank, offs, ssrc, N_EDGES_C);

    // ---- features -> fp16 into hm0 h-part; weights -> fp16 transposed ----
    const int n4 = N_NODES_C * K_FEAT / 4;
    f2h_kernel<<<(n4 + 255) / 256, 256, 0, stream>>>(feat, hm0, n4);
    wconv_all_kernel<<<(81920 + 255) / 256, 256, 0, stream>>>(
        Ws0, Wn0, Ws1, Wn1, Ws2, Wn2, WT0, WT1, WT2);

    const int meanBlocks = (N_NODES_C * 64 + 255) / 256;
    const int gemmBlocks = (N_NODES_C + 127) / 128;  // 391

    // ---- layer 0 ----
    mean_kernel<<<meanBlocks, 256, 0, stream>>>(hm0, offs, ssrc);
    sage_mfma<128, true, false><<<gemmBlocks, 256, 0, stream>>>(
        hm0, WT0, b0, nullptr, hm1, N_NODES_C);

    // ---- layer 1 ----
    mean_kernel<<<meanBlocks, 256, 0, stream>>>(hm1, offs, ssrc);
    sage_mfma<128, true, false><<<gemmBlocks, 256, 0, stream>>>(
        hm1, WT1, b1, nullptr, hm2, N_NODES_C);

    // ---- layer 2 ----
    mean_kernel<<<meanBlocks, 256, 0, stream>>>(hm2, offs, ssrc);
    sage_mfma<64, false, true><<<gemmBlocks, 256, 0, stream>>>(
        hm2, WT2, b2, out, nullptr, N_NODES_C);
}

// Round 7
// 202.540 us; speedup vs baseline: 2.7169x; 1.0302x over previous
//
#include <hip/hip_runtime.h>
#include <hip/hip_fp16.h>

#define N_NODES_C 50000
#define N_EDGES_C 800000
#define K_FEAT 128
#define HM_STRIDE 256  // [h(128) | mean(128)] fp16 per node

typedef unsigned int uint_t;
typedef _Float16 half8 __attribute__((ext_vector_type(8)));
typedef _Float16 half4 __attribute__((ext_vector_type(4)));
typedef float f32x4 __attribute__((ext_vector_type(4)));

// ---------------- workspace zero (replaces runtime fillBuffer in graph) ----------------

__global__ void zero_kernel(int4* __restrict__ p, int n4) {
    int i = blockIdx.x * blockDim.x + threadIdx.x;
    if (i < n4) p[i] = make_int4(0, 0, 0, 0);
}

// ---------------- CSR build ----------------

// Counting atomic doubles as rank assignment: rank[i] = #earlier edges with same dst.
__global__ void count_rank_kernel(const int* __restrict__ dst, int* __restrict__ cnt,
                                  int* __restrict__ rank, int E) {
    int i = blockIdx.x * blockDim.x + threadIdx.x;
    if (i < E) rank[i] = atomicAdd(&cnt[dst[i]], 1);
}

// Hierarchical scan, step 1: 256 threads x 4 elems = 1024/block.
__global__ void scan1_kernel(const int* __restrict__ cnt, int* __restrict__ offs,
                             int* __restrict__ bsums, int n) {
    const int t = threadIdx.x;
    const int lane = t & 63;
    const int wid = t >> 6;
    const int base = blockIdx.x * 1024 + t * 4;
    int v[4];
#pragma unroll
    for (int j = 0; j < 4; ++j) v[j] = (base + j < n) ? cnt[base + j] : 0;
    int s = v[0] + v[1] + v[2] + v[3];
    int x = s;
#pragma unroll
    for (int off = 1; off < 64; off <<= 1) {
        int y = __shfl_up(x, off, 64);
        if (lane >= off) x += y;
    }
    __shared__ int wsum[4];
    if (lane == 63) wsum[wid] = x;
    __syncthreads();
    int wpre = 0;
#pragma unroll
    for (int w = 0; w < 4; ++w)
        if (w < wid) wpre += wsum[w];
    int run = wpre + x - s;
#pragma unroll
    for (int j = 0; j < 4; ++j) {
        if (base + j < n) offs[base + j] = run;
        run += v[j];
    }
    if (t == 255) bsums[blockIdx.x] = wpre + x;
}

__global__ void scan2_kernel(int* __restrict__ bsums, int nb) {
    const int lane = threadIdx.x;
    int v = (lane < nb) ? bsums[lane] : 0;
    int x = v;
#pragma unroll
    for (int off = 1; off < 64; off <<= 1) {
        int y = __shfl_up(x, off, 64);
        if (lane >= off) x += y;
    }
    if (lane < nb) bsums[lane] = x - v;
}

__global__ void scan3_kernel(int* __restrict__ offs, const int* __restrict__ bsums,
                             int n, int total) {
    const int t = threadIdx.x;
    const int base = blockIdx.x * 1024 + t * 4;
    const int add = bsums[blockIdx.x];
#pragma unroll
    for (int j = 0; j < 4; ++j) {
        int idx = base + j;
        if (idx < n) offs[idx] += add;
    }
    if (blockIdx.x == 0 && t == 0) offs[n] = total;
}

// Atomic-free fill: ssrc[offs[dst] + rank] = src. 4 edges/thread, independent chains.
__global__ void fill_kernel(const int* __restrict__ src, const int* __restrict__ dst,
                            const int* __restrict__ rank, const int* __restrict__ offs,
                            int* __restrict__ ssrc, int E) {
    const int i = (blockIdx.x * blockDim.x + threadIdx.x) * 4;
    if (i + 4 <= E) {
        int4 s = *reinterpret_cast<const int4*>(src + i);
        int4 d = *reinterpret_cast<const int4*>(dst + i);
        int4 r = *reinterpret_cast<const int4*>(rank + i);
        int o0 = offs[d.x], o1 = offs[d.y], o2 = offs[d.z], o3 = offs[d.w];
        ssrc[o0 + r.x] = s.x;
        ssrc[o1 + r.y] = s.y;
        ssrc[o2 + r.z] = s.z;
        ssrc[o3 + r.w] = s.w;
    } else {
        for (int j = i; j < E; ++j) ssrc[offs[dst[j]] + rank[j]] = src[j];
    }
}

// ---------------- fp32 features -> fp16 h-part of hm0 ----------------

__global__ void f2h_kernel(const float* __restrict__ in, _Float16* __restrict__ hm, int n4) {
    int i = blockIdx.x * blockDim.x + threadIdx.x;
    if (i < n4) {
        float4 v = reinterpret_cast<const float4*>(in)[i];
        int n = i >> 5, c4 = i & 31;  // 32 float4 per 128-col row
        half4 o;
        o.x = (_Float16)v.x; o.y = (_Float16)v.y; o.z = (_Float16)v.z; o.w = (_Float16)v.w;
        *reinterpret_cast<half4*>(hm + (size_t)n * HM_STRIDE + c4 * 4) = o;
    }
}

// ---------------- weight convert+transpose, all 3 layers in one launch ----------------
// WT[c][k] = Wcat[k][c] fp16; Wcat rows 0..127 = Ws, 128..255 = Wn.

__global__ void wconv_all_kernel(const float* __restrict__ Ws0, const float* __restrict__ Wn0,
                                 const float* __restrict__ Ws1, const float* __restrict__ Wn1,
                                 const float* __restrict__ Ws2, const float* __restrict__ Wn2,
                                 _Float16* __restrict__ WT0, _Float16* __restrict__ WT1,
                                 _Float16* __restrict__ WT2) {
    int idx = blockIdx.x * blockDim.x + threadIdx.x;
    const float* Ws;
    const float* Wn;
    _Float16* WT;
    int ncol;
    if (idx < 32768) { Ws = Ws0; Wn = Wn0; WT = WT0; ncol = 128; }
    else if (idx < 65536) { idx -= 32768; Ws = Ws1; Wn = Wn1; WT = WT1; ncol = 128; }
    else if (idx < 81920) { idx -= 65536; Ws = Ws2; Wn = Wn2; WT = WT2; ncol = 64; }
    else return;
    int k = idx & 255, c = idx >> 8;
    float v = (k < 128) ? Ws[(size_t)k * ncol + c] : Wn[(size_t)(k - 128) * ncol + c];
    WT[(size_t)c * 256 + k] = (_Float16)v;
}

// ---------------- mean aggregation: one wave per node, 4 edge-rows per vmem instr ----
// Lane group g=lane>>4 handles edge e+g; lane covers col-block (lane&15)*8 (16B).
// One wave-load = 64 lanes x 16B = 4 full rows. 2 loads/iter = 8 edges in flight.
// Cross-group combine: shfl_xor 16 & 32; lanes 0-15 store half8.

__global__ void mean_kernel(_Float16* __restrict__ hm, const int* __restrict__ offs,
                            const int* __restrict__ ssrc) {
    const int node = (int)((blockIdx.x * blockDim.x + threadIdx.x) >> 6);
    const int lane = threadIdx.x & 63;
    if (node >= N_NODES_C) return;
    const int beg = offs[node], end = offs[node + 1];
    const int g = lane >> 4;
    const int cb = (lane & 15) * 8;
    const _Float16* base = hm + cb;

    float accA[8] = {0.f, 0.f, 0.f, 0.f, 0.f, 0.f, 0.f, 0.f};
    float accB[8] = {0.f, 0.f, 0.f, 0.f, 0.f, 0.f, 0.f, 0.f};

    int e = beg;
    for (; e + 8 <= end; e += 8) {
        const int s0 = ssrc[e + g];
        const int s1 = ssrc[e + 4 + g];
        half8 v0 = *reinterpret_cast<const half8*>(base + (size_t)s0 * HM_STRIDE);
        half8 v1 = *reinterpret_cast<const half8*>(base + (size_t)s1 * HM_STRIDE);
#pragma unroll
        for (int j = 0; j < 8; ++j) accA[j] += (float)v0[j];
#pragma unroll
        for (int j = 0; j < 8; ++j) accB[j] += (float)v1[j];
    }
    for (; e + 4 <= end; e += 4) {
        const int s0 = ssrc[e + g];
        half8 v0 = *reinterpret_cast<const half8*>(base + (size_t)s0 * HM_STRIDE);
#pragma unroll
        for (int j = 0; j < 8; ++j) accA[j] += (float)v0[j];
    }
    if (e < end) {
        const bool valid = (e + g) < end;
        const int s0 = valid ? ssrc[e + g] : ssrc[beg];  // beg<end here, safe addr
        half8 v0 = *reinterpret_cast<const half8*>(base + (size_t)s0 * HM_STRIDE);
        if (valid) {
#pragma unroll
            for (int j = 0; j < 8; ++j) accB[j] += (float)v0[j];
        }
    }

    const float inv = (end > beg) ? 1.0f / (float)(end - beg) : 0.f;
    half8 o;
#pragma unroll
    for (int j = 0; j < 8; ++j) {
        float x = accA[j] + accB[j];
        x += __shfl_xor(x, 16, 64);
        x += __shfl_xor(x, 32, 64);
        o[j] = (_Float16)(x * inv);
    }
    if (lane < 16)
        *reinterpret_cast<half8*>(hm + (size_t)node * HM_STRIDE + 128 + cb) = o;
}

// ---------------- MFMA GEMM: out = act(hm @ Wcat + b), K=256 ----------------
// Block: 256 threads (4 waves), 128 rows (32/wave). WT staged in LDS (XOR-swizzled).
// All 16 A-frags preloaded to registers, then pure LDS+MFMA.
// C/D mapping: col=lane&15, row=(lane>>4)*4+reg (m89-verified).

template <int NCOL, bool ACT, bool OUT_FP32>
__global__ __launch_bounds__(256) void sage_mfma(
    const _Float16* __restrict__ hm,  // [n][256]
    const _Float16* __restrict__ WT,  // [NCOL][256]
    const float* __restrict__ bias,
    float* __restrict__ outf,         // OUT_FP32: [n][NCOL]
    _Float16* __restrict__ outh,      // else: next layer's hm, h-part
    int nNodes) {
    constexpr int CF = NCOL / 16;  // col frags: 8 or 4
    constexpr int RPW = 32;        // rows per wave
    constexpr int RPB = 128;       // rows per block

    __shared__ _Float16 bl[NCOL][256];  // 64KB / 32KB

    const int t = threadIdx.x;
#pragma unroll
    for (int it = 0; it < NCOL * 32 / 256; ++it) {
        int f = t + it * 256;
        int row = f >> 5, c8 = f & 31;
        half8 v = *reinterpret_cast<const half8*>(WT + (size_t)row * 256 + c8 * 8);
        int col = (c8 * 8) ^ ((row & 7) << 3);
        *reinterpret_cast<half8*>(&bl[row][col]) = v;
    }
    __syncthreads();

    const int wid = t >> 6;
    const int lane = t & 63;
    const int r0 = blockIdx.x * RPB + wid * RPW;
    const int koff = (lane >> 4) * 8;

    half8 a[2][8];
#pragma unroll
    for (int fr = 0; fr < 2; ++fr) {
        int row = r0 + fr * 16 + (lane & 15);
        if (row >= nNodes) row = nNodes - 1;
        const _Float16* ap = hm + (size_t)row * HM_STRIDE + koff;
#pragma unroll
        for (int ks = 0; ks < 8; ++ks)
            a[fr][ks] = *reinterpret_cast<const half8*>(ap + ks * 32);
    }

    f32x4 acc[2][CF];
#pragma unroll
    for (int fr = 0; fr < 2; ++fr)
#pragma unroll
        for (int c = 0; c < CF; ++c) acc[fr][c] = {0.f, 0.f, 0.f, 0.f};

#pragma unroll
    for (int c = 0; c < CF; ++c) {
        const int brow = c * 16 + (lane & 15);
        const int bswz = (brow & 7) << 3;
#pragma unroll
        for (int ks = 0; ks < 8; ++ks) {
            half8 b = *reinterpret_cast<const half8*>(&bl[brow][(ks * 32 + koff) ^ bswz]);
            acc[0][c] = __builtin_amdgcn_mfma_f32_16x16x32_f16(a[0][ks], b, acc[0][c], 0, 0, 0);
            acc[1][c] = __builtin_amdgcn_mfma_f32_16x16x32_f16(a[1][ks], b, acc[1][c], 0, 0, 0);
        }
    }

    const int ocol = lane & 15;
    const int orow_off = (lane >> 4) << 2;
#pragma unroll
    for (int fr = 0; fr < 2; ++fr) {
        const int rbase = r0 + fr * 16 + orow_off;
#pragma unroll
        for (int c = 0; c < CF; ++c) {
            const int col = c * 16 + ocol;
            const float bv = bias[col];
#pragma unroll
            for (int reg = 0; reg < 4; ++reg) {
                const int row = rbase + reg;
                if (row < nNodes) {
                    float v = acc[fr][c][reg] + bv;
                    if (ACT) v = fmaxf(v, 0.f);
                    if (OUT_FP32) outf[(size_t)row * NCOL + col] = v;
                    else outh[(size_t)row * HM_STRIDE + col] = (_Float16)v;
                }
            }
        }
    }
}

// ---------------- launch ----------------

extern "C" void kernel_launch(void* const* d_in, const int* in_sizes, int n_in,
                              void* d_out, int out_size, void* d_ws, size_t ws_size,
                              hipStream_t stream) {
    const float* feat = (const float*)d_in[0];
    const int* src = (const int*)d_in[1];
    const int* dst = (const int*)d_in[2];
    const float* Ws0 = (const float*)d_in[3];
    const float* Wn0 = (const float*)d_in[4];
    const float* b0 = (const float*)d_in[5];
    const float* Ws1 = (const float*)d_in[6];
    const float* Wn1 = (const float*)d_in[7];
    const float* b1 = (const float*)d_in[8];
    const float* Ws2 = (const float*)d_in[9];
    const float* Wn2 = (const float*)d_in[10];
    const float* b2 = (const float*)d_in[11];
    float* out = (float*)d_out;

    auto align_up = [](size_t x) { return (x + 255) & ~(size_t)255; };
    char* w = (char*)d_ws;
    int* cnt = (int*)w;     w += align_up((size_t)N_NODES_C * 4);
    int* offs = (int*)w;    w += align_up((size_t)(N_NODES_C + 1) * 4);
    int* bsums = (int*)w;   w += align_up(64 * 4);
    int* rank = (int*)w;    w += align_up((size_t)N_EDGES_C * 4);
    int* ssrc = (int*)w;    w += align_up((size_t)N_EDGES_C * 4);
    _Float16* hm0 = (_Float16*)w; w += align_up((size_t)N_NODES_C * HM_STRIDE * 2);
    _Float16* hm1 = (_Float16*)w; w += align_up((size_t)N_NODES_C * HM_STRIDE * 2);
    _Float16* WT0 = (_Float16*)w; w += align_up((size_t)128 * 256 * 2);
    _Float16* WT1 = (_Float16*)w; w += align_up((size_t)128 * 256 * 2);
    _Float16* WT2 = (_Float16*)w; w += align_up((size_t)64 * 256 * 2);
    _Float16* hm2 = hm0;  // hm0 is dead after GEMM0 reads it

    const int scanBlocks = (N_NODES_C + 1023) / 1024;  // 49
    const int edgeBlocks = (N_EDGES_C + 255) / 256;    // 3125
    const int edge4Blocks = (N_EDGES_C / 4 + 255) / 256;  // 782

    // ---- CSR build ----
    zero_kernel<<<(N_NODES_C / 4 + 255) / 256, 256, 0, stream>>>((int4*)cnt, N_NODES_C / 4);
    count_rank_kernel<<<edgeBlocks, 256, 0, stream>>>(dst, cnt, rank, N_EDGES_C);
    scan1_kernel<<<scanBlocks, 256, 0, stream>>>(cnt, offs, bsums, N_NODES_C);
    scan2_kernel<<<1, 64, 0, stream>>>(bsums, scanBlocks);
    scan3_kernel<<<scanBlocks, 256, 0, stream>>>(offs, bsums, N_NODES_C, N_EDGES_C);
    fill_kernel<<<edge4Blocks, 256, 0, stream>>>(src, dst, rank, offs, ssrc, N_EDGES_C);

    // ---- features -> fp16 into hm0 h-part; weights -> fp16 transposed ----
    const int n4 = N_NODES_C * K_FEAT / 4;
    f2h_kernel<<<(n4 + 255) / 256, 256, 0, stream>>>(feat, hm0, n4);
    wconv_all_kernel<<<(81920 + 255) / 256, 256, 0, stream>>>(
        Ws0, Wn0, Ws1, Wn1, Ws2, Wn2, WT0, WT1, WT2);

    const int meanBlocks = (N_NODES_C * 64 + 255) / 256;
    const int gemmBlocks = (N_NODES_C + 127) / 128;  // 391

    // ---- layer 0 ----
    mean_kernel<<<meanBlocks, 256, 0, stream>>>(hm0, offs, ssrc);
    sage_mfma<128, true, false><<<gemmBlocks, 256, 0, stream>>>(
        hm0, WT0, b0, nullptr, hm1, N_NODES_C);

    // ---- layer 1 ----
    mean_kernel<<<meanBlocks, 256, 0, stream>>>(hm1, offs, ssrc);
    sage_mfma<128, true, false><<<gemmBlocks, 256, 0, stream>>>(
        hm1, WT1, b1, nullptr, hm2, N_NODES_C);

    // ---- layer 2 ----
    mean_kernel<<<meanBlocks, 256, 0, stream>>>(hm2, offs, ssrc);
    sage_mfma<64, false, true><<<gemmBlocks, 256, 0, stream>>>(
        hm2, WT2, b2, out, nullptr, N_NODES_C);
}